// Round 16
// baseline (2786.298 us; speedup 1.0000x reference)
//
#include <hip/hip_runtime.h>
#include <stdint.h>

#define NB 8
#define NPT 16384
#define NM 1024
#define NK 32

// ws layout (float element offsets)
#define WS_W0T 0                    // 67*64 = 4288   W0t[c][o] = W0[o][c]*s0[o]
#define WS_B0  (WS_W0T + 4288)      // 64             b0*s0+t0
#define WS_W1T (WS_B0 + 64)         // 64*128 = 8192
#define WS_B1  (WS_W1T + 8192)      // 128
#define WS_W2T (WS_B1 + 128)        // 128*256 = 32768
#define WS_B2  (WS_W2T + 32768)     // 256
#define WS_IDX (WS_B2 + 256)        // 8192 ints (FPS indices)
#define WS_NXYZ (WS_IDX + 8192)     // 8*1024*3 = 24576 floats
#define WS_BALL (WS_NXYZ + 24576)   // 8*1024*32 = 262144 ints

// out layout (float element offsets)
#define OUT_XYZ 0
#define OUT_FEAT 24576
#define OUT_IDX (24576 + 2097152)

typedef float fx2 __attribute__((ext_vector_type(2)));

// ---------------- weight prep: transpose + fold BN scale ----------------
__global__ void prep_weights(const float* __restrict__ W0, const float* __restrict__ b0,
                             const float* __restrict__ s0, const float* __restrict__ t0,
                             const float* __restrict__ W1, const float* __restrict__ b1,
                             const float* __restrict__ s1, const float* __restrict__ t1,
                             const float* __restrict__ W2, const float* __restrict__ b2,
                             const float* __restrict__ s2, const float* __restrict__ t2,
                             float* __restrict__ ws) {
    int id = blockIdx.x * 256 + threadIdx.x;
    if (id < 4288) { int c = id >> 6, o = id & 63;  ws[WS_W0T + id] = W0[o * 67 + c] * s0[o]; return; }
    id -= 4288;
    if (id < 64)   { ws[WS_B0 + id] = fmaf(b0[id], s0[id], t0[id]); return; }
    id -= 64;
    if (id < 8192) { int c = id >> 7, o = id & 127; ws[WS_W1T + id] = W1[o * 64 + c] * s1[o]; return; }
    id -= 8192;
    if (id < 128)  { ws[WS_B1 + id] = fmaf(b1[id], s1[id], t1[id]); return; }
    id -= 128;
    if (id < 32768){ int c = id >> 8, o = id & 255; ws[WS_W2T + id] = W2[o * 128 + c] * s2[o]; return; }
    id -= 32768;
    if (id < 256)  { ws[WS_B2 + id] = fmaf(b2[id], s2[id], t2[id]); return; }
}

#define FOREACH8(M) M(0) M(1) M(2) M(3) M(4) M(5) M(6) M(7)

// DPP u32-max step (dpp_ctrl must be an IMMEDIATE -> template param).
// Invalid/unmasked lanes inherit `old`=v, so result is max over the reached set.
// ctrl: 0x111/112/114/118 = row_shr 1/2/4/8, 0x142 = row_bcast:15, 0x143 = row_bcast:31.
template <int CTRL>
__device__ __forceinline__ uint32_t dpp_max_step(uint32_t v) {
    uint32_t o = (uint32_t)__builtin_amdgcn_update_dpp((int)v, (int)v, CTRL, 0xf, 0xf, false);
    return v > o ? v : o;
}
__device__ __forceinline__ uint32_t wave_max_u32(uint32_t v) {
    v = dpp_max_step<0x111>(v);
    v = dpp_max_step<0x112>(v);
    v = dpp_max_step<0x114>(v);
    v = dpp_max_step<0x118>(v);
    v = dpp_max_step<0x142>(v);
    v = dpp_max_step<0x143>(v);
    return v;
}
__device__ __forceinline__ uint32_t row_max_u32(uint32_t v) {
    v = dpp_max_step<0x111>(v);
    v = dpp_max_step<0x112>(v);
    v = dpp_max_step<0x114>(v);
    v = dpp_max_step<0x118>(v);
    return v;
}

// ---------------- farthest point sampling v9: pk-math + pair-major b128 LDS ----------------
// R15 lesson: fps8's "(t<<3)|(p^t7)" layout put lane t at 128B stride -> all lanes'
// bank index collapsed to (p^t7)*4 -> 8-way serialization, SQ_LDS_BANK_CONFLICT
// 4.19M and +65us. Textbook fix (same class as fps7's 0-conflict b64 pattern):
// PAIR-MAJOR layout P4[p*1024 + t] so lane t reads base_p + t*16 -- consecutive
// lanes, consecutive 16B. pk-math kept (bitwise == scalar, HW-validated R8/R15
// passed): sub as x + (-c) exact; each pk half one RN f32 op. z pairs + dd in
// named-scalar VGPRs (~52, no spill). DPP argmax/reduce unchanged (validated
// R14): u32 keys = non-negative float bits, tie via max(~idx) == min(idx),
// readlane -> uniform centroid -> scalar loads. Pair order p asc, .x then .y +
// strict '>' => first-max-wins exact.
__global__ __attribute__((amdgpu_flat_work_group_size(1024, 1024)))
void fps9_kernel(const float* __restrict__ xyz, int* __restrict__ out_idx) {
    __shared__ float4 P4[NPT / 2];       // 8192 slots x 16B = 128 KB, pair-major
    __shared__ uint2 s_red[2][16];       // {lo=~idx, hi=dist bits} per wave
    int b = blockIdx.x, t = threadIdx.x;
    const float* __restrict__ Xp = xyz + (size_t)b * NPT * 3;

#define DECL_PAIR(p) fx2 zz##p; float ddA##p, ddB##p;
    FOREACH8(DECL_PAIR)
#undef DECL_PAIR

#define LOAD_PAIR(p) { int j0 = t + (2 * (p)) * 1024, j1 = t + (2 * (p) + 1) * 1024; \
        float x0 = Xp[j0 * 3 + 0], y0 = Xp[j0 * 3 + 1]; zz##p.x = Xp[j0 * 3 + 2]; \
        float x1 = Xp[j1 * 3 + 0], y1 = Xp[j1 * 3 + 1]; zz##p.y = Xp[j1 * 3 + 2]; \
        P4[(p) * 1024 + t] = make_float4(x0, x1, y0, y1); \
        ddA##p = 1e10f; ddB##p = 1e10f; }
    FOREACH8(LOAD_PAIR)
#undef LOAD_PAIR
    __syncthreads();

    int farthest = 0;
    float cx = Xp[0], cy = Xp[1], cz = Xp[2];
    int lane = t & 63, w = t >> 6;
    for (int it = 0; it < NM; ++it) {
        if (t == 0) out_idx[b * NM + it] = farthest;
        float mcx = -cx, mcy = -cy, mcz = -cz;
        fx2 ncx; ncx.x = mcx; ncx.y = mcx;
        fx2 ncy; ncy.x = mcy; ncy.y = mcy;
        fx2 ncz; ncz.x = mcz; ncz.y = mcz;
        float best = -1.0f; int bi = 0;
        // p + (-c) bitwise == p - c; each pk half = one RN f32 op (HW-validated).
        // pairs ascend (j = 2p, 2p+1), strict '>' => first-max wins in-thread.
#define STEP_PAIR(p) { float4 A = P4[(p) * 1024 + t]; \
        fx2 xx; xx.x = A.x; xx.y = A.y; \
        fx2 yy; yy.x = A.z; yy.y = A.w; \
        fx2 dx, dy, dz, sxy, d; \
        asm("v_pk_add_f32 %0, %1, %2" : "=v"(dx) : "v"(xx), "v"(ncx)); \
        asm("v_pk_add_f32 %0, %1, %2" : "=v"(dy) : "v"(yy), "v"(ncy)); \
        asm("v_pk_add_f32 %0, %1, %2" : "=v"(dz) : "v"(zz##p), "v"(ncz)); \
        asm("v_pk_mul_f32 %0, %1, %1" : "=v"(dx) : "v"(dx)); \
        asm("v_pk_mul_f32 %0, %1, %1" : "=v"(dy) : "v"(dy)); \
        asm("v_pk_mul_f32 %0, %1, %1" : "=v"(dz) : "v"(dz)); \
        asm("v_pk_add_f32 %0, %1, %2" : "=v"(sxy) : "v"(dx), "v"(dy)); \
        asm("v_pk_add_f32 %0, %1, %2" : "=v"(d) : "v"(sxy), "v"(dz)); \
        ddA##p = fminf(ddA##p, d.x); \
        if (ddA##p > best) { best = ddA##p; bi = t + (2 * (p)) * 1024; } \
        ddB##p = fminf(ddB##p, d.y); \
        if (ddB##p > best) { best = ddB##p; bi = t + (2 * (p) + 1) * 1024; } }
        FOREACH8(STEP_PAIR)
#undef STEP_PAIR
        // wave argmax: u32 DPP max of dist bits, then exact tie-resolve via max(~idx).
        uint32_t bbits = __float_as_uint(best);
        uint32_t wmax = __builtin_amdgcn_readlane(wave_max_u32(bbits), 63);
        uint32_t cand = (bbits == wmax) ? ~(uint32_t)bi : 0u;
        uint32_t cwin = __builtin_amdgcn_readlane(wave_max_u32(cand), 63);
        if (lane == 0) s_red[it & 1][w] = make_uint2(cwin, wmax);
        __syncthreads();
        uint2 e = s_red[it & 1][lane & 15];
        uint32_t hmax = __builtin_amdgcn_readlane(row_max_u32(e.y), 15);
        uint32_t c2 = (e.y == hmax) ? e.x : 0u;
        uint32_t c2w = __builtin_amdgcn_readlane(row_max_u32(c2), 15);
        int widx = (int)(~c2w);
        farthest = widx;
        const float* cp = Xp + (size_t)widx * 3;   // widx uniform -> scalar loads
        cx = cp[0]; cy = cp[1]; cz = cp[2];
    }
}

// ---------------- gather new_xyz + emit indices as float ----------------
__global__ void gather_newxyz(const float* __restrict__ xyz, const int* __restrict__ idx_ws,
                              float* __restrict__ nxyz_ws, float* __restrict__ out_xyz,
                              float* __restrict__ out_idx_f) {
    int id = blockIdx.x * 256 + threadIdx.x;
    if (id >= NB * NM) return;
    int b = id / NM;
    int p = idx_ws[id];
    const float* Xp = xyz + ((size_t)b * NPT + p) * 3;
    float x = Xp[0], y = Xp[1], z = Xp[2];
    nxyz_ws[id * 3 + 0] = x; nxyz_ws[id * 3 + 1] = y; nxyz_ws[id * 3 + 2] = z;
    out_xyz[id * 3 + 0] = x; out_xyz[id * 3 + 1] = y; out_xyz[id * 3 + 2] = z;
    out_idx_f[id] = (float)p;
}

// ---------------- ball query: first 32 in-radius indices (ascending) ----------------
__global__ __launch_bounds__(256) void ball_query_kernel(const float* __restrict__ xyz,
                                                         const float* __restrict__ nxyz,
                                                         int* __restrict__ ball) {
    int blk = blockIdx.x;
    int b = blk >> 10;
    int t = threadIdx.x;
    const float* Xp = xyz + (size_t)b * NPT * 3;
    float cx = nxyz[blk * 3 + 0], cy = nxyz[blk * 3 + 1], cz = nxyz[blk * 3 + 2];
    const float r2 = (float)(0.4 * 0.4);
    uint64_t mask = 0;
    int base = t * 64;
    const float4* q = (const float4*)(Xp + (size_t)base * 3);
#pragma unroll 4
    for (int c = 0; c < 16; c++) {
        float4 A = q[c * 3 + 0], B = q[c * 3 + 1], C = q[c * 3 + 2];
        float xs[4] = {A.x, A.w, B.z, C.y};
        float ys[4] = {A.y, B.x, B.w, C.z};
        float zs[4] = {A.z, B.y, C.x, C.w};
#pragma unroll
        for (int u = 0; u < 4; u++) {
            float dx = __fsub_rn(xs[u], cx);
            float dy = __fsub_rn(ys[u], cy);
            float dz = __fsub_rn(zs[u], cz);
            float d2 = __fadd_rn(__fadd_rn(__fmul_rn(dx, dx), __fmul_rn(dy, dy)), __fmul_rn(dz, dz));
            if (d2 <= r2) mask |= (1ull << (c * 4 + u));
        }
    }
    int cnt = __popcll(mask);
    int scan = cnt;
    for (int off = 1; off < 64; off <<= 1) {
        int nv = __shfl_up(scan, off);
        if ((t & 63) >= off) scan += nv;
    }
    __shared__ int s_wsum[4];
    __shared__ int s_hit[32];
    int w = t >> 6;
    if ((t & 63) == 63) s_wsum[w] = scan;
    __syncthreads();
    int woff = 0;
    for (int i = 0; i < 4; i++) if (i < w) woff += s_wsum[i];
    int excl = woff + scan - cnt;
    uint64_t mm = mask; int pos = excl;
    while (mm && pos < 32) {
        int j = __ffsll((long long)mm) - 1;
        s_hit[pos] = base + j;
        pos++;
        mm &= mm - 1;
    }
    __syncthreads();
    int total = s_wsum[0] + s_wsum[1] + s_wsum[2] + s_wsum[3];
    if (t < 32) {
        int first = s_hit[0];
        ball[blk * NK + t] = (t < total) ? s_hit[t] : first;
    }
}

// ---------------- fused group + 3xMLP + max over K ----------------
// Union buffer u = Xs/h2 -> LDS 48KB -> 3 blocks/CU (12 waves) for better latency
// hiding on the L2 weight-load chains.
__global__ __attribute__((amdgpu_flat_work_group_size(256, 256), amdgpu_waves_per_eu(3, 3)))
void fused_mlp_kernel(const float* __restrict__ xyz,
                      const float* __restrict__ feats,
                      const float* __restrict__ ws_f,
                      const int* __restrict__ ball,
                      const float* __restrict__ nxyz,
                      float* __restrict__ out_feat) {
    int blk = blockIdx.x;
    int b = blk >> 9;
    int m0 = (blk & 511) * 2;
    int t = threadIdx.x;
    int k = t & 31, g = t >> 5;
    __shared__ float u[2][128][32];      // Xs (rows 0..66) then h2 (rows 0..127)
    __shared__ float h1[2][64][32];
    __shared__ int sidx[2][32];
    const float* W0t = ws_f + WS_W0T; const float* b0f = ws_f + WS_B0;
    const float* W1t = ws_f + WS_W1T; const float* b1f = ws_f + WS_B1;
    const float* W2t = ws_f + WS_W2T; const float* b2f = ws_f + WS_B2;

    if (t < 64) {
        int ctr = t >> 5;
        sidx[ctr][t & 31] = ball[((size_t)b * NM + m0 + ctr) * NK + (t & 31)];
    }
    __syncthreads();

    const float* Xp = xyz + (size_t)b * NPT * 3;
    if (g < 6) {
        int ctr = g / 3, dim = g % 3;
        float cc = nxyz[((size_t)b * NM + m0 + ctr) * 3 + dim];
        u[ctr][dim][k] = Xp[sidx[ctr][k] * 3 + dim] - cc;
    }
    const float* Fp = feats + (size_t)b * 64 * NPT;
#pragma unroll
    for (int i = 0; i < 8; i++) {
        int c = g + 8 * i;
        u[0][3 + c][k] = Fp[(size_t)c * NPT + sidx[0][k]];
        u[1][3 + c][k] = Fp[(size_t)c * NPT + sidx[1][k]];
    }
    __syncthreads();

    // layer 1: 67 -> 64 (reads u rows 0..66, writes h1)
    {
        float acc0[8], acc1[8];
#pragma unroll
        for (int i = 0; i < 8; i++) { acc0[i] = b0f[g * 8 + i]; acc1[i] = acc0[i]; }
#pragma unroll 4
        for (int c = 0; c < 67; c++) {
            float xv0 = u[0][c][k], xv1 = u[1][c][k];
            const float* wr = W0t + c * 64 + g * 8;
            float4 wa = *(const float4*)(wr), wb = *(const float4*)(wr + 4);
            acc0[0] = fmaf(wa.x, xv0, acc0[0]); acc1[0] = fmaf(wa.x, xv1, acc1[0]);
            acc0[1] = fmaf(wa.y, xv0, acc0[1]); acc1[1] = fmaf(wa.y, xv1, acc1[1]);
            acc0[2] = fmaf(wa.z, xv0, acc0[2]); acc1[2] = fmaf(wa.z, xv1, acc1[2]);
            acc0[3] = fmaf(wa.w, xv0, acc0[3]); acc1[3] = fmaf(wa.w, xv1, acc1[3]);
            acc0[4] = fmaf(wb.x, xv0, acc0[4]); acc1[4] = fmaf(wb.x, xv1, acc1[4]);
            acc0[5] = fmaf(wb.y, xv0, acc0[5]); acc1[5] = fmaf(wb.y, xv1, acc1[5]);
            acc0[6] = fmaf(wb.z, xv0, acc0[6]); acc1[6] = fmaf(wb.z, xv1, acc1[6]);
            acc0[7] = fmaf(wb.w, xv0, acc0[7]); acc1[7] = fmaf(wb.w, xv1, acc1[7]);
        }
#pragma unroll
        for (int i = 0; i < 8; i++) {
            h1[0][g * 8 + i][k] = fmaxf(acc0[i], 0.0f);
            h1[1][g * 8 + i][k] = fmaxf(acc1[i], 0.0f);
        }
    }
    __syncthreads();

    // layer 2: 64 -> 128 (reads h1, writes h2 into u; Xs dead)
    {
        float acc0[16], acc1[16];
#pragma unroll
        for (int i = 0; i < 16; i++) { acc0[i] = b1f[g * 16 + i]; acc1[i] = acc0[i]; }
#pragma unroll 4
        for (int c = 0; c < 64; c++) {
            float xv0 = h1[0][c][k], xv1 = h1[1][c][k];
            const float4* wr = (const float4*)(W1t + c * 128 + g * 16);
#pragma unroll
            for (int q = 0; q < 4; q++) {
                float4 wv = wr[q];
                acc0[q * 4 + 0] = fmaf(wv.x, xv0, acc0[q * 4 + 0]); acc1[q * 4 + 0] = fmaf(wv.x, xv1, acc1[q * 4 + 0]);
                acc0[q * 4 + 1] = fmaf(wv.y, xv0, acc0[q * 4 + 1]); acc1[q * 4 + 1] = fmaf(wv.y, xv1, acc1[q * 4 + 1]);
                acc0[q * 4 + 2] = fmaf(wv.z, xv0, acc0[q * 4 + 2]); acc1[q * 4 + 2] = fmaf(wv.z, xv1, acc1[q * 4 + 2]);
                acc0[q * 4 + 3] = fmaf(wv.w, xv0, acc0[q * 4 + 3]); acc1[q * 4 + 3] = fmaf(wv.w, xv1, acc1[q * 4 + 3]);
            }
        }
        __syncthreads();   // ensure all layer-1 reads of u are done before overwrite
#pragma unroll
        for (int i = 0; i < 16; i++) {
            u[0][g * 16 + i][k] = fmaxf(acc0[i], 0.0f);
            u[1][g * 16 + i][k] = fmaxf(acc1[i], 0.0f);
        }
    }
    __syncthreads();

    // layer 3: 128 -> 256 in two half-passes (reads h2 from u), then max over k
#pragma unroll
    for (int half = 0; half < 2; half++) {
        float acc0[16], acc1[16];
#pragma unroll
        for (int i = 0; i < 16; i++) { acc0[i] = b2f[g * 32 + half * 16 + i]; acc1[i] = acc0[i]; }
#pragma unroll 4
        for (int c = 0; c < 128; c++) {
            float xv0 = u[0][c][k], xv1 = u[1][c][k];
            const float4* wr = (const float4*)(W2t + c * 256 + g * 32 + half * 16);
#pragma unroll
            for (int q = 0; q < 4; q++) {
                float4 wv = wr[q];
                acc0[q * 4 + 0] = fmaf(wv.x, xv0, acc0[q * 4 + 0]); acc1[q * 4 + 0] = fmaf(wv.x, xv1, acc1[q * 4 + 0]);
                acc0[q * 4 + 1] = fmaf(wv.y, xv0, acc0[q * 4 + 1]); acc1[q * 4 + 1] = fmaf(wv.y, xv1, acc1[q * 4 + 1]);
                acc0[q * 4 + 2] = fmaf(wv.z, xv0, acc0[q * 4 + 2]); acc1[q * 4 + 2] = fmaf(wv.z, xv1, acc1[q * 4 + 2]);
                acc0[q * 4 + 3] = fmaf(wv.w, xv0, acc0[q * 4 + 3]); acc1[q * 4 + 3] = fmaf(wv.w, xv1, acc1[q * 4 + 3]);
            }
        }
#pragma unroll
        for (int i = 0; i < 16; i++) {
            float v0 = fmaxf(acc0[i], 0.0f);
            float v1 = fmaxf(acc1[i], 0.0f);
#pragma unroll
            for (int off = 16; off >= 1; off >>= 1) {
                v0 = fmaxf(v0, __shfl_xor(v0, off));
                v1 = fmaxf(v1, __shfl_xor(v1, off));
            }
            if (k == 0) {
                size_t o = (size_t)b * 256 + g * 32 + half * 16 + i;
                out_feat[o * NM + m0]     = v0;
                out_feat[o * NM + m0 + 1] = v1;
            }
        }
    }
}

extern "C" void kernel_launch(void* const* d_in, const int* in_sizes, int n_in,
                              void* d_out, int out_size, void* d_ws, size_t ws_size,
                              hipStream_t stream) {
    const float* xyz   = (const float*)d_in[0];
    const float* feats = (const float*)d_in[1];
    const float* W0 = (const float*)d_in[2];  const float* b0 = (const float*)d_in[3];
    const float* s0 = (const float*)d_in[4];  const float* t0 = (const float*)d_in[5];
    const float* W1 = (const float*)d_in[6];  const float* b1 = (const float*)d_in[7];
    const float* s1 = (const float*)d_in[8];  const float* t1 = (const float*)d_in[9];
    const float* W2 = (const float*)d_in[10]; const float* b2 = (const float*)d_in[11];
    const float* s2 = (const float*)d_in[12]; const float* t2 = (const float*)d_in[13];

    float* ws_f = (float*)d_ws;
    int*   idx_ws  = (int*)(ws_f + WS_IDX);
    float* nxyz_ws = ws_f + WS_NXYZ;
    int*   ball_ws = (int*)(ws_f + WS_BALL);

    float* out_f = (float*)d_out;
    float* out_xyz  = out_f + OUT_XYZ;
    float* out_feat = out_f + OUT_FEAT;
    float* out_idxf = out_f + OUT_IDX;

    prep_weights<<<179, 256, 0, stream>>>(W0, b0, s0, t0, W1, b1, s1, t1, W2, b2, s2, t2, ws_f);
    fps9_kernel<<<NB, 1024, 0, stream>>>(xyz, idx_ws);
    gather_newxyz<<<32, 256, 0, stream>>>(xyz, idx_ws, nxyz_ws, out_xyz, out_idxf);
    ball_query_kernel<<<NB * NM, 256, 0, stream>>>(xyz, nxyz_ws, ball_ws);
    fused_mlp_kernel<<<NB * NM / 2, 256, 0, stream>>>(xyz, feats, ws_f, ball_ws, nxyz_ws, out_feat);
}

// Round 17
// 2783.879 us; speedup vs baseline: 1.0009x; 1.0009x over previous
//
#include <hip/hip_runtime.h>
#include <stdint.h>

#define NB 8
#define NPT 16384
#define NM 1024
#define NK 32

// ws layout (float element offsets)
#define WS_W0T 0                    // 67*64 = 4288   W0t[c][o] = W0[o][c]*s0[o]
#define WS_B0  (WS_W0T + 4288)      // 64             b0*s0+t0
#define WS_W1T (WS_B0 + 64)         // 64*128 = 8192
#define WS_B1  (WS_W1T + 8192)      // 128
#define WS_W2T (WS_B1 + 128)        // 128*256 = 32768
#define WS_B2  (WS_W2T + 32768)     // 256
#define WS_IDX (WS_B2 + 256)        // 8192 ints (FPS indices)
#define WS_NXYZ (WS_IDX + 8192)     // 8*1024*3 = 24576 floats
#define WS_BALL (WS_NXYZ + 24576)   // 8*1024*32 = 262144 ints

// out layout (float element offsets)
#define OUT_XYZ 0
#define OUT_FEAT 24576
#define OUT_IDX (24576 + 2097152)

typedef float fx2 __attribute__((ext_vector_type(2)));

// ---------------- weight prep: transpose + fold BN scale ----------------
__global__ void prep_weights(const float* __restrict__ W0, const float* __restrict__ b0,
                             const float* __restrict__ s0, const float* __restrict__ t0,
                             const float* __restrict__ W1, const float* __restrict__ b1,
                             const float* __restrict__ s1, const float* __restrict__ t1,
                             const float* __restrict__ W2, const float* __restrict__ b2,
                             const float* __restrict__ s2, const float* __restrict__ t2,
                             float* __restrict__ ws) {
    int id = blockIdx.x * 256 + threadIdx.x;
    if (id < 4288) { int c = id >> 6, o = id & 63;  ws[WS_W0T + id] = W0[o * 67 + c] * s0[o]; return; }
    id -= 4288;
    if (id < 64)   { ws[WS_B0 + id] = fmaf(b0[id], s0[id], t0[id]); return; }
    id -= 64;
    if (id < 8192) { int c = id >> 7, o = id & 127; ws[WS_W1T + id] = W1[o * 64 + c] * s1[o]; return; }
    id -= 8192;
    if (id < 128)  { ws[WS_B1 + id] = fmaf(b1[id], s1[id], t1[id]); return; }
    id -= 128;
    if (id < 32768){ int c = id >> 8, o = id & 255; ws[WS_W2T + id] = W2[o * 128 + c] * s2[o]; return; }
    id -= 32768;
    if (id < 256)  { ws[WS_B2 + id] = fmaf(b2[id], s2[id], t2[id]); return; }
}

#define FOREACH8(M) M(0) M(1) M(2) M(3) M(4) M(5) M(6) M(7)

// DPP u32-max step (dpp_ctrl must be an IMMEDIATE -> template param).
// Invalid/unmasked lanes inherit `old`=v, so result is max over the reached set.
// ctrl: 0x111/112/114/118 = row_shr 1/2/4/8, 0x142 = row_bcast:15, 0x143 = row_bcast:31.
template <int CTRL>
__device__ __forceinline__ uint32_t dpp_max_step(uint32_t v) {
    uint32_t o = (uint32_t)__builtin_amdgcn_update_dpp((int)v, (int)v, CTRL, 0xf, 0xf, false);
    return v > o ? v : o;
}
__device__ __forceinline__ uint32_t wave_max_u32(uint32_t v) {
    v = dpp_max_step<0x111>(v);
    v = dpp_max_step<0x112>(v);
    v = dpp_max_step<0x114>(v);
    v = dpp_max_step<0x118>(v);
    v = dpp_max_step<0x142>(v);
    v = dpp_max_step<0x143>(v);
    return v;
}
__device__ __forceinline__ uint32_t row_max_u32(uint32_t v) {
    v = dpp_max_step<0x111>(v);
    v = dpp_max_step<0x112>(v);
    v = dpp_max_step<0x114>(v);
    v = dpp_max_step<0x118>(v);
    return v;
}

// ---------------- farthest point sampling v9: pk-math + pair-major b128 LDS ----------------
// R15 lesson: fps8's "(t<<3)|(p^t7)" layout put lane t at 128B stride -> all lanes'
// bank index collapsed to (p^t7)*4 -> 8-way serialization, SQ_LDS_BANK_CONFLICT
// 4.19M and +65us. Textbook fix (same class as fps7's 0-conflict b64 pattern):
// PAIR-MAJOR layout P4[p*1024 + t] so lane t reads base_p + t*16 -- consecutive
// lanes, consecutive 16B. pk-math kept (bitwise == scalar, HW-validated R8/R15
// passed): sub as x + (-c) exact; each pk half one RN f32 op. z pairs + dd in
// named-scalar VGPRs (~52, no spill). DPP argmax/reduce unchanged (validated
// R14): u32 keys = non-negative float bits, tie via max(~idx) == min(idx),
// readlane -> uniform centroid -> scalar loads. Pair order p asc, .x then .y +
// strict '>' => first-max-wins exact.
__global__ __attribute__((amdgpu_flat_work_group_size(1024, 1024)))
void fps9_kernel(const float* __restrict__ xyz, int* __restrict__ out_idx) {
    __shared__ float4 P4[NPT / 2];       // 8192 slots x 16B = 128 KB, pair-major
    __shared__ uint2 s_red[2][16];       // {lo=~idx, hi=dist bits} per wave
    int b = blockIdx.x, t = threadIdx.x;
    const float* __restrict__ Xp = xyz + (size_t)b * NPT * 3;

#define DECL_PAIR(p) fx2 zz##p; float ddA##p, ddB##p;
    FOREACH8(DECL_PAIR)
#undef DECL_PAIR

#define LOAD_PAIR(p) { int j0 = t + (2 * (p)) * 1024, j1 = t + (2 * (p) + 1) * 1024; \
        float x0 = Xp[j0 * 3 + 0], y0 = Xp[j0 * 3 + 1]; zz##p.x = Xp[j0 * 3 + 2]; \
        float x1 = Xp[j1 * 3 + 0], y1 = Xp[j1 * 3 + 1]; zz##p.y = Xp[j1 * 3 + 2]; \
        P4[(p) * 1024 + t] = make_float4(x0, x1, y0, y1); \
        ddA##p = 1e10f; ddB##p = 1e10f; }
    FOREACH8(LOAD_PAIR)
#undef LOAD_PAIR
    __syncthreads();

    int farthest = 0;
    float cx = Xp[0], cy = Xp[1], cz = Xp[2];
    int lane = t & 63, w = t >> 6;
    for (int it = 0; it < NM; ++it) {
        if (t == 0) out_idx[b * NM + it] = farthest;
        float mcx = -cx, mcy = -cy, mcz = -cz;
        fx2 ncx; ncx.x = mcx; ncx.y = mcx;
        fx2 ncy; ncy.x = mcy; ncy.y = mcy;
        fx2 ncz; ncz.x = mcz; ncz.y = mcz;
        float best = -1.0f; int bi = 0;
        // p + (-c) bitwise == p - c; each pk half = one RN f32 op (HW-validated).
        // pairs ascend (j = 2p, 2p+1), strict '>' => first-max wins in-thread.
#define STEP_PAIR(p) { float4 A = P4[(p) * 1024 + t]; \
        fx2 xx; xx.x = A.x; xx.y = A.y; \
        fx2 yy; yy.x = A.z; yy.y = A.w; \
        fx2 dx, dy, dz, sxy, d; \
        asm("v_pk_add_f32 %0, %1, %2" : "=v"(dx) : "v"(xx), "v"(ncx)); \
        asm("v_pk_add_f32 %0, %1, %2" : "=v"(dy) : "v"(yy), "v"(ncy)); \
        asm("v_pk_add_f32 %0, %1, %2" : "=v"(dz) : "v"(zz##p), "v"(ncz)); \
        asm("v_pk_mul_f32 %0, %1, %1" : "=v"(dx) : "v"(dx)); \
        asm("v_pk_mul_f32 %0, %1, %1" : "=v"(dy) : "v"(dy)); \
        asm("v_pk_mul_f32 %0, %1, %1" : "=v"(dz) : "v"(dz)); \
        asm("v_pk_add_f32 %0, %1, %2" : "=v"(sxy) : "v"(dx), "v"(dy)); \
        asm("v_pk_add_f32 %0, %1, %2" : "=v"(d) : "v"(sxy), "v"(dz)); \
        ddA##p = fminf(ddA##p, d.x); \
        if (ddA##p > best) { best = ddA##p; bi = t + (2 * (p)) * 1024; } \
        ddB##p = fminf(ddB##p, d.y); \
        if (ddB##p > best) { best = ddB##p; bi = t + (2 * (p) + 1) * 1024; } }
        FOREACH8(STEP_PAIR)
#undef STEP_PAIR
        // wave argmax: u32 DPP max of dist bits, then exact tie-resolve via max(~idx).
        uint32_t bbits = __float_as_uint(best);
        uint32_t wmax = __builtin_amdgcn_readlane(wave_max_u32(bbits), 63);
        uint32_t cand = (bbits == wmax) ? ~(uint32_t)bi : 0u;
        uint32_t cwin = __builtin_amdgcn_readlane(wave_max_u32(cand), 63);
        if (lane == 0) s_red[it & 1][w] = make_uint2(cwin, wmax);
        __syncthreads();
        uint2 e = s_red[it & 1][lane & 15];
        uint32_t hmax = __builtin_amdgcn_readlane(row_max_u32(e.y), 15);
        uint32_t c2 = (e.y == hmax) ? e.x : 0u;
        uint32_t c2w = __builtin_amdgcn_readlane(row_max_u32(c2), 15);
        int widx = (int)(~c2w);
        farthest = widx;
        const float* cp = Xp + (size_t)widx * 3;   // widx uniform -> scalar loads
        cx = cp[0]; cy = cp[1]; cz = cp[2];
    }
}

// ---------------- gather new_xyz + emit indices as float ----------------
__global__ void gather_newxyz(const float* __restrict__ xyz, const int* __restrict__ idx_ws,
                              float* __restrict__ nxyz_ws, float* __restrict__ out_xyz,
                              float* __restrict__ out_idx_f) {
    int id = blockIdx.x * 256 + threadIdx.x;
    if (id >= NB * NM) return;
    int b = id / NM;
    int p = idx_ws[id];
    const float* Xp = xyz + ((size_t)b * NPT + p) * 3;
    float x = Xp[0], y = Xp[1], z = Xp[2];
    nxyz_ws[id * 3 + 0] = x; nxyz_ws[id * 3 + 1] = y; nxyz_ws[id * 3 + 2] = z;
    out_xyz[id * 3 + 0] = x; out_xyz[id * 3 + 1] = y; out_xyz[id * 3 + 2] = z;
    out_idx_f[id] = (float)p;
}

// ---------------- ball query: first 32 in-radius indices (ascending) ----------------
__global__ __launch_bounds__(256) void ball_query_kernel(const float* __restrict__ xyz,
                                                         const float* __restrict__ nxyz,
                                                         int* __restrict__ ball) {
    int blk = blockIdx.x;
    int b = blk >> 10;
    int t = threadIdx.x;
    const float* Xp = xyz + (size_t)b * NPT * 3;
    float cx = nxyz[blk * 3 + 0], cy = nxyz[blk * 3 + 1], cz = nxyz[blk * 3 + 2];
    const float r2 = (float)(0.4 * 0.4);
    uint64_t mask = 0;
    int base = t * 64;
    const float4* q = (const float4*)(Xp + (size_t)base * 3);
#pragma unroll 4
    for (int c = 0; c < 16; c++) {
        float4 A = q[c * 3 + 0], B = q[c * 3 + 1], C = q[c * 3 + 2];
        float xs[4] = {A.x, A.w, B.z, C.y};
        float ys[4] = {A.y, B.x, B.w, C.z};
        float zs[4] = {A.z, B.y, C.x, C.w};
#pragma unroll
        for (int u = 0; u < 4; u++) {
            float dx = __fsub_rn(xs[u], cx);
            float dy = __fsub_rn(ys[u], cy);
            float dz = __fsub_rn(zs[u], cz);
            float d2 = __fadd_rn(__fadd_rn(__fmul_rn(dx, dx), __fmul_rn(dy, dy)), __fmul_rn(dz, dz));
            if (d2 <= r2) mask |= (1ull << (c * 4 + u));
        }
    }
    int cnt = __popcll(mask);
    int scan = cnt;
    for (int off = 1; off < 64; off <<= 1) {
        int nv = __shfl_up(scan, off);
        if ((t & 63) >= off) scan += nv;
    }
    __shared__ int s_wsum[4];
    __shared__ int s_hit[32];
    int w = t >> 6;
    if ((t & 63) == 63) s_wsum[w] = scan;
    __syncthreads();
    int woff = 0;
    for (int i = 0; i < 4; i++) if (i < w) woff += s_wsum[i];
    int excl = woff + scan - cnt;
    uint64_t mm = mask; int pos = excl;
    while (mm && pos < 32) {
        int j = __ffsll((long long)mm) - 1;
        s_hit[pos] = base + j;
        pos++;
        mm &= mm - 1;
    }
    __syncthreads();
    int total = s_wsum[0] + s_wsum[1] + s_wsum[2] + s_wsum[3];
    if (t < 32) {
        int first = s_hit[0];
        ball[blk * NK + t] = (t < total) ? s_hit[t] : first;
    }
}

// ---------------- fused group + 3xMLP + max over K ----------------
// Union buffer u = Xs/h2 -> LDS 48KB -> 3 blocks/CU (12 waves) for better latency
// hiding on the L2 weight-load chains.
__global__ __attribute__((amdgpu_flat_work_group_size(256, 256), amdgpu_waves_per_eu(3, 3)))
void fused_mlp_kernel(const float* __restrict__ xyz,
                      const float* __restrict__ feats,
                      const float* __restrict__ ws_f,
                      const int* __restrict__ ball,
                      const float* __restrict__ nxyz,
                      float* __restrict__ out_feat) {
    int blk = blockIdx.x;
    int b = blk >> 9;
    int m0 = (blk & 511) * 2;
    int t = threadIdx.x;
    int k = t & 31, g = t >> 5;
    __shared__ float u[2][128][32];      // Xs (rows 0..66) then h2 (rows 0..127)
    __shared__ float h1[2][64][32];
    __shared__ int sidx[2][32];
    const float* W0t = ws_f + WS_W0T; const float* b0f = ws_f + WS_B0;
    const float* W1t = ws_f + WS_W1T; const float* b1f = ws_f + WS_B1;
    const float* W2t = ws_f + WS_W2T; const float* b2f = ws_f + WS_B2;

    if (t < 64) {
        int ctr = t >> 5;
        sidx[ctr][t & 31] = ball[((size_t)b * NM + m0 + ctr) * NK + (t & 31)];
    }
    __syncthreads();

    const float* Xp = xyz + (size_t)b * NPT * 3;
    if (g < 6) {
        int ctr = g / 3, dim = g % 3;
        float cc = nxyz[((size_t)b * NM + m0 + ctr) * 3 + dim];
        u[ctr][dim][k] = Xp[sidx[ctr][k] * 3 + dim] - cc;
    }
    const float* Fp = feats + (size_t)b * 64 * NPT;
#pragma unroll
    for (int i = 0; i < 8; i++) {
        int c = g + 8 * i;
        u[0][3 + c][k] = Fp[(size_t)c * NPT + sidx[0][k]];
        u[1][3 + c][k] = Fp[(size_t)c * NPT + sidx[1][k]];
    }
    __syncthreads();

    // layer 1: 67 -> 64 (reads u rows 0..66, writes h1)
    {
        float acc0[8], acc1[8];
#pragma unroll
        for (int i = 0; i < 8; i++) { acc0[i] = b0f[g * 8 + i]; acc1[i] = acc0[i]; }
#pragma unroll 4
        for (int c = 0; c < 67; c++) {
            float xv0 = u[0][c][k], xv1 = u[1][c][k];
            const float* wr = W0t + c * 64 + g * 8;
            float4 wa = *(const float4*)(wr), wb = *(const float4*)(wr + 4);
            acc0[0] = fmaf(wa.x, xv0, acc0[0]); acc1[0] = fmaf(wa.x, xv1, acc1[0]);
            acc0[1] = fmaf(wa.y, xv0, acc0[1]); acc1[1] = fmaf(wa.y, xv1, acc1[1]);
            acc0[2] = fmaf(wa.z, xv0, acc0[2]); acc1[2] = fmaf(wa.z, xv1, acc1[2]);
            acc0[3] = fmaf(wa.w, xv0, acc0[3]); acc1[3] = fmaf(wa.w, xv1, acc1[3]);
            acc0[4] = fmaf(wb.x, xv0, acc0[4]); acc1[4] = fmaf(wb.x, xv1, acc1[4]);
            acc0[5] = fmaf(wb.y, xv0, acc0[5]); acc1[5] = fmaf(wb.y, xv1, acc1[5]);
            acc0[6] = fmaf(wb.z, xv0, acc0[6]); acc1[6] = fmaf(wb.z, xv1, acc1[6]);
            acc0[7] = fmaf(wb.w, xv0, acc0[7]); acc1[7] = fmaf(wb.w, xv1, acc1[7]);
        }
#pragma unroll
        for (int i = 0; i < 8; i++) {
            h1[0][g * 8 + i][k] = fmaxf(acc0[i], 0.0f);
            h1[1][g * 8 + i][k] = fmaxf(acc1[i], 0.0f);
        }
    }
    __syncthreads();

    // layer 2: 64 -> 128 (reads h1, writes h2 into u; Xs dead)
    {
        float acc0[16], acc1[16];
#pragma unroll
        for (int i = 0; i < 16; i++) { acc0[i] = b1f[g * 16 + i]; acc1[i] = acc0[i]; }
#pragma unroll 4
        for (int c = 0; c < 64; c++) {
            float xv0 = h1[0][c][k], xv1 = h1[1][c][k];
            const float4* wr = (const float4*)(W1t + c * 128 + g * 16);
#pragma unroll
            for (int q = 0; q < 4; q++) {
                float4 wv = wr[q];
                acc0[q * 4 + 0] = fmaf(wv.x, xv0, acc0[q * 4 + 0]); acc1[q * 4 + 0] = fmaf(wv.x, xv1, acc1[q * 4 + 0]);
                acc0[q * 4 + 1] = fmaf(wv.y, xv0, acc0[q * 4 + 1]); acc1[q * 4 + 1] = fmaf(wv.y, xv1, acc1[q * 4 + 1]);
                acc0[q * 4 + 2] = fmaf(wv.z, xv0, acc0[q * 4 + 2]); acc1[q * 4 + 2] = fmaf(wv.z, xv1, acc1[q * 4 + 2]);
                acc0[q * 4 + 3] = fmaf(wv.w, xv0, acc0[q * 4 + 3]); acc1[q * 4 + 3] = fmaf(wv.w, xv1, acc1[q * 4 + 3]);
            }
        }
        __syncthreads();   // ensure all layer-1 reads of u are done before overwrite
#pragma unroll
        for (int i = 0; i < 16; i++) {
            u[0][g * 16 + i][k] = fmaxf(acc0[i], 0.0f);
            u[1][g * 16 + i][k] = fmaxf(acc1[i], 0.0f);
        }
    }
    __syncthreads();

    // layer 3: 128 -> 256 in two half-passes (reads h2 from u), then max over k
#pragma unroll
    for (int half = 0; half < 2; half++) {
        float acc0[16], acc1[16];
#pragma unroll
        for (int i = 0; i < 16; i++) { acc0[i] = b2f[g * 32 + half * 16 + i]; acc1[i] = acc0[i]; }
#pragma unroll 4
        for (int c = 0; c < 128; c++) {
            float xv0 = u[0][c][k], xv1 = u[1][c][k];
            const float4* wr = (const float4*)(W2t + c * 256 + g * 32 + half * 16);
#pragma unroll
            for (int q = 0; q < 4; q++) {
                float4 wv = wr[q];
                acc0[q * 4 + 0] = fmaf(wv.x, xv0, acc0[q * 4 + 0]); acc1[q * 4 + 0] = fmaf(wv.x, xv1, acc1[q * 4 + 0]);
                acc0[q * 4 + 1] = fmaf(wv.y, xv0, acc0[q * 4 + 1]); acc1[q * 4 + 1] = fmaf(wv.y, xv1, acc1[q * 4 + 1]);
                acc0[q * 4 + 2] = fmaf(wv.z, xv0, acc0[q * 4 + 2]); acc1[q * 4 + 2] = fmaf(wv.z, xv1, acc1[q * 4 + 2]);
                acc0[q * 4 + 3] = fmaf(wv.w, xv0, acc0[q * 4 + 3]); acc1[q * 4 + 3] = fmaf(wv.w, xv1, acc1[q * 4 + 3]);
            }
        }
#pragma unroll
        for (int i = 0; i < 16; i++) {
            float v0 = fmaxf(acc0[i], 0.0f);
            float v1 = fmaxf(acc1[i], 0.0f);
#pragma unroll
            for (int off = 16; off >= 1; off >>= 1) {
                v0 = fmaxf(v0, __shfl_xor(v0, off));
                v1 = fmaxf(v1, __shfl_xor(v1, off));
            }
            if (k == 0) {
                size_t o = (size_t)b * 256 + g * 32 + half * 16 + i;
                out_feat[o * NM + m0]     = v0;
                out_feat[o * NM + m0 + 1] = v1;
            }
        }
    }
}

extern "C" void kernel_launch(void* const* d_in, const int* in_sizes, int n_in,
                              void* d_out, int out_size, void* d_ws, size_t ws_size,
                              hipStream_t stream) {
    const float* xyz   = (const float*)d_in[0];
    const float* feats = (const float*)d_in[1];
    const float* W0 = (const float*)d_in[2];  const float* b0 = (const float*)d_in[3];
    const float* s0 = (const float*)d_in[4];  const float* t0 = (const float*)d_in[5];
    const float* W1 = (const float*)d_in[6];  const float* b1 = (const float*)d_in[7];
    const float* s1 = (const float*)d_in[8];  const float* t1 = (const float*)d_in[9];
    const float* W2 = (const float*)d_in[10]; const float* b2 = (const float*)d_in[11];
    const float* s2 = (const float*)d_in[12]; const float* t2 = (const float*)d_in[13];

    float* ws_f = (float*)d_ws;
    int*   idx_ws  = (int*)(ws_f + WS_IDX);
    float* nxyz_ws = ws_f + WS_NXYZ;
    int*   ball_ws = (int*)(ws_f + WS_BALL);

    float* out_f = (float*)d_out;
    float* out_xyz  = out_f + OUT_XYZ;
    float* out_feat = out_f + OUT_FEAT;
    float* out_idxf = out_f + OUT_IDX;

    prep_weights<<<179, 256, 0, stream>>>(W0, b0, s0, t0, W1, b1, s1, t1, W2, b2, s2, t2, ws_f);
    fps9_kernel<<<NB, 1024, 0, stream>>>(xyz, idx_ws);
    gather_newxyz<<<32, 256, 0, stream>>>(xyz, idx_ws, nxyz_ws, out_xyz, out_idxf);
    ball_query_kernel<<<NB * NM, 256, 0, stream>>>(xyz, nxyz_ws, ball_ws);
    fused_mlp_kernel<<<NB * NM / 2, 256, 0, stream>>>(xyz, feats, ws_f, ball_ws, nxyz_ws, out_feat);
}

// Round 18
// 2689.503 us; speedup vs baseline: 1.0360x; 1.0351x over previous
//
#include <hip/hip_runtime.h>
#include <stdint.h>

#define NB 8
#define NPT 16384
#define NM 1024
#define NK 32

// ws layout (float element offsets)
#define WS_W0T 0                    // 67*64 = 4288   W0t[c][o] = W0[o][c]*s0[o]
#define WS_B0  (WS_W0T + 4288)      // 64             b0*s0+t0
#define WS_W1T (WS_B0 + 64)         // 64*128 = 8192
#define WS_B1  (WS_W1T + 8192)      // 128
#define WS_W2T (WS_B1 + 128)        // 128*256 = 32768
#define WS_B2  (WS_W2T + 32768)     // 256
#define WS_IDX (WS_B2 + 256)        // 8192 ints (FPS indices)
#define WS_NXYZ (WS_IDX + 8192)     // 8*1024*3 = 24576 floats
#define WS_BALL (WS_NXYZ + 24576)   // 8*1024*32 = 262144 ints

// out layout (float element offsets)
#define OUT_XYZ 0
#define OUT_FEAT 24576
#define OUT_IDX (24576 + 2097152)

// ---------------- weight prep: transpose + fold BN scale ----------------
__global__ void prep_weights(const float* __restrict__ W0, const float* __restrict__ b0,
                             const float* __restrict__ s0, const float* __restrict__ t0,
                             const float* __restrict__ W1, const float* __restrict__ b1,
                             const float* __restrict__ s1, const float* __restrict__ t1,
                             const float* __restrict__ W2, const float* __restrict__ b2,
                             const float* __restrict__ s2, const float* __restrict__ t2,
                             float* __restrict__ ws) {
    int id = blockIdx.x * 256 + threadIdx.x;
    if (id < 4288) { int c = id >> 6, o = id & 63;  ws[WS_W0T + id] = W0[o * 67 + c] * s0[o]; return; }
    id -= 4288;
    if (id < 64)   { ws[WS_B0 + id] = fmaf(b0[id], s0[id], t0[id]); return; }
    id -= 64;
    if (id < 8192) { int c = id >> 7, o = id & 127; ws[WS_W1T + id] = W1[o * 64 + c] * s1[o]; return; }
    id -= 8192;
    if (id < 128)  { ws[WS_B1 + id] = fmaf(b1[id], s1[id], t1[id]); return; }
    id -= 128;
    if (id < 32768){ int c = id >> 8, o = id & 255; ws[WS_W2T + id] = W2[o * 128 + c] * s2[o]; return; }
    id -= 32768;
    if (id < 256)  { ws[WS_B2 + id] = fmaf(b2[id], s2[id], t2[id]); return; }
}

#define FOREACH16(M) M(0) M(1) M(2) M(3) M(4) M(5) M(6) M(7) \
                     M(8) M(9) M(10) M(11) M(12) M(13) M(14) M(15)

// DPP u32-max step (dpp_ctrl must be an IMMEDIATE -> template param).
// Invalid/unmasked lanes inherit `old`=v, so result is max over the reached set.
// ctrl: 0x111/112/114/118 = row_shr 1/2/4/8, 0x142 = row_bcast:15, 0x143 = row_bcast:31.
template <int CTRL>
__device__ __forceinline__ uint32_t dpp_max_step(uint32_t v) {
    uint32_t o = (uint32_t)__builtin_amdgcn_update_dpp((int)v, (int)v, CTRL, 0xf, 0xf, false);
    return v > o ? v : o;
}
__device__ __forceinline__ uint32_t wave_max_u32(uint32_t v) {
    v = dpp_max_step<0x111>(v);
    v = dpp_max_step<0x112>(v);
    v = dpp_max_step<0x114>(v);
    v = dpp_max_step<0x118>(v);
    v = dpp_max_step<0x142>(v);
    v = dpp_max_step<0x143>(v);
    return v;
}
__device__ __forceinline__ uint32_t row_max_u32(uint32_t v) {
    v = dpp_max_step<0x111>(v);
    v = dpp_max_step<0x112>(v);
    v = dpp_max_step<0x114>(v);
    v = dpp_max_step<0x118>(v);
    return v;
}

// ---------------- farthest point sampling v10 = fps7 (R14 best, 1770us) + LDS centroid ----------------
// R15/R17 lesson: pk-math + b128 variants (fps8/fps9) cut VALUBusy but ran SLOWER
// than fps7 -- the inline-asm pk path defeats the compiler's ds_read offset folding
// and scheduling. fps7's scalar path at 96% of the 8-CU issue ceiling is the best
// structure found. One tweak kept: the dependent per-iteration centroid reload takes
// cx,cy from the LDS payload (pxy[widx], same-address broadcast ds_read ~120cyc)
// instead of the ~200cyc L2 global load; z (not in LDS) stays a scalar global load
// overlapping on a different counter. Bit-exact: pxy holds exact copies of x,y.
// Payload: (x,y) in LDS (128 KB), z+dd in named-scalar VGPRs (~52, no spill).
// DPP argmax (validated R14): u32 keys = non-negative float bits, u32 cmp == f32
// cmp; tie via max(~idx) == min(idx); in-thread order j asc = orig-idx asc + strict
// '>' => first-max-wins exact. One barrier/iter, parity-double-buffered s_red.
__global__ __attribute__((amdgpu_flat_work_group_size(1024, 1024)))
void fps10_kernel(const float* __restrict__ xyz, int* __restrict__ out_idx) {
    __shared__ float2 pxy[NPT];          // 128 KB
    __shared__ uint2 s_red[2][16];       // {lo=~idx, hi=dist bits} per wave
    int b = blockIdx.x, t = threadIdx.x;
    const float* __restrict__ Xp = xyz + (size_t)b * NPT * 3;

#define DECL_PT(j) float pz##j, dd##j;
    FOREACH16(DECL_PT)
#undef DECL_PT

#define LOAD_PT(j) { int p = t + (j) * 1024; \
        float x = Xp[p * 3 + 0], y = Xp[p * 3 + 1]; \
        pz##j = Xp[p * 3 + 2]; \
        pxy[p] = make_float2(x, y); \
        dd##j = 1e10f; }
    FOREACH16(LOAD_PT)
#undef LOAD_PT
    __syncthreads();

    int farthest = 0;
    float cx = Xp[0], cy = Xp[1], cz = Xp[2];
    int lane = t & 63, w = t >> 6;
    for (int it = 0; it < NM; ++it) {
        if (t == 0) out_idx[b * NM + it] = farthest;
        float best = -1.0f; int bi = 0;
        // ascending j + strict '>' => first-max wins in-thread (idx = t + j*1024 ascends with j)
#define STEP_PT(j) { \
        float2 q = pxy[t + (j) * 1024]; \
        float dx = __fsub_rn(q.x, cx); \
        float dy = __fsub_rn(q.y, cy); \
        float dz = __fsub_rn(pz##j, cz); \
        float d  = __fadd_rn(__fadd_rn(__fmul_rn(dx, dx), __fmul_rn(dy, dy)), __fmul_rn(dz, dz)); \
        dd##j = fminf(dd##j, d); \
        if (dd##j > best) { best = dd##j; bi = t + (j) * 1024; } }
        FOREACH16(STEP_PT)
#undef STEP_PT
        // wave argmax: u32 DPP max of dist bits, then exact tie-resolve via max(~idx).
        uint32_t bbits = __float_as_uint(best);
        uint32_t wmax = __builtin_amdgcn_readlane(wave_max_u32(bbits), 63);
        uint32_t cand = (bbits == wmax) ? ~(uint32_t)bi : 0u;
        uint32_t cwin = __builtin_amdgcn_readlane(wave_max_u32(cand), 63);
        if (lane == 0) s_red[it & 1][w] = make_uint2(cwin, wmax);
        __syncthreads();
        // 16-entry tail: row-only DPP (all rows read identical data)
        uint2 e = s_red[it & 1][lane & 15];
        uint32_t hmax = __builtin_amdgcn_readlane(row_max_u32(e.y), 15);
        uint32_t c2 = (e.y == hmax) ? e.x : 0u;
        uint32_t c2w = __builtin_amdgcn_readlane(row_max_u32(c2), 15);
        int widx = (int)(~c2w);
        farthest = widx;
        // centroid: x,y from LDS payload (same-addr broadcast, ~120cyc, bit-exact copy);
        // z from global (scalar, uniform addr) overlapping on vmcnt/lgkmcnt.
        float2 cc = pxy[widx];
        cx = cc.x; cy = cc.y;
        cz = Xp[(size_t)widx * 3 + 2];
    }
}

// ---------------- gather new_xyz + emit indices as float ----------------
__global__ void gather_newxyz(const float* __restrict__ xyz, const int* __restrict__ idx_ws,
                              float* __restrict__ nxyz_ws, float* __restrict__ out_xyz,
                              float* __restrict__ out_idx_f) {
    int id = blockIdx.x * 256 + threadIdx.x;
    if (id >= NB * NM) return;
    int b = id / NM;
    int p = idx_ws[id];
    const float* Xp = xyz + ((size_t)b * NPT + p) * 3;
    float x = Xp[0], y = Xp[1], z = Xp[2];
    nxyz_ws[id * 3 + 0] = x; nxyz_ws[id * 3 + 1] = y; nxyz_ws[id * 3 + 2] = z;
    out_xyz[id * 3 + 0] = x; out_xyz[id * 3 + 1] = y; out_xyz[id * 3 + 2] = z;
    out_idx_f[id] = (float)p;
}

// ---------------- ball query: first 32 in-radius indices (ascending) ----------------
__global__ __launch_bounds__(256) void ball_query_kernel(const float* __restrict__ xyz,
                                                         const float* __restrict__ nxyz,
                                                         int* __restrict__ ball) {
    int blk = blockIdx.x;
    int b = blk >> 10;
    int t = threadIdx.x;
    const float* Xp = xyz + (size_t)b * NPT * 3;
    float cx = nxyz[blk * 3 + 0], cy = nxyz[blk * 3 + 1], cz = nxyz[blk * 3 + 2];
    const float r2 = (float)(0.4 * 0.4);
    uint64_t mask = 0;
    int base = t * 64;
    const float4* q = (const float4*)(Xp + (size_t)base * 3);
#pragma unroll 4
    for (int c = 0; c < 16; c++) {
        float4 A = q[c * 3 + 0], B = q[c * 3 + 1], C = q[c * 3 + 2];
        float xs[4] = {A.x, A.w, B.z, C.y};
        float ys[4] = {A.y, B.x, B.w, C.z};
        float zs[4] = {A.z, B.y, C.x, C.w};
#pragma unroll
        for (int u = 0; u < 4; u++) {
            float dx = __fsub_rn(xs[u], cx);
            float dy = __fsub_rn(ys[u], cy);
            float dz = __fsub_rn(zs[u], cz);
            float d2 = __fadd_rn(__fadd_rn(__fmul_rn(dx, dx), __fmul_rn(dy, dy)), __fmul_rn(dz, dz));
            if (d2 <= r2) mask |= (1ull << (c * 4 + u));
        }
    }
    int cnt = __popcll(mask);
    int scan = cnt;
    for (int off = 1; off < 64; off <<= 1) {
        int nv = __shfl_up(scan, off);
        if ((t & 63) >= off) scan += nv;
    }
    __shared__ int s_wsum[4];
    __shared__ int s_hit[32];
    int w = t >> 6;
    if ((t & 63) == 63) s_wsum[w] = scan;
    __syncthreads();
    int woff = 0;
    for (int i = 0; i < 4; i++) if (i < w) woff += s_wsum[i];
    int excl = woff + scan - cnt;
    uint64_t mm = mask; int pos = excl;
    while (mm && pos < 32) {
        int j = __ffsll((long long)mm) - 1;
        s_hit[pos] = base + j;
        pos++;
        mm &= mm - 1;
    }
    __syncthreads();
    int total = s_wsum[0] + s_wsum[1] + s_wsum[2] + s_wsum[3];
    if (t < 32) {
        int first = s_hit[0];
        ball[blk * NK + t] = (t < total) ? s_hit[t] : first;
    }
}

// ---------------- fused group + 3xMLP + max over K ----------------
// Union buffer u = Xs/h2 -> LDS 48KB -> 3 blocks/CU (12 waves) for better latency
// hiding on the L2 weight-load chains.
__global__ __attribute__((amdgpu_flat_work_group_size(256, 256), amdgpu_waves_per_eu(3, 3)))
void fused_mlp_kernel(const float* __restrict__ xyz,
                      const float* __restrict__ feats,
                      const float* __restrict__ ws_f,
                      const int* __restrict__ ball,
                      const float* __restrict__ nxyz,
                      float* __restrict__ out_feat) {
    int blk = blockIdx.x;
    int b = blk >> 9;
    int m0 = (blk & 511) * 2;
    int t = threadIdx.x;
    int k = t & 31, g = t >> 5;
    __shared__ float u[2][128][32];      // Xs (rows 0..66) then h2 (rows 0..127)
    __shared__ float h1[2][64][32];
    __shared__ int sidx[2][32];
    const float* W0t = ws_f + WS_W0T; const float* b0f = ws_f + WS_B0;
    const float* W1t = ws_f + WS_W1T; const float* b1f = ws_f + WS_B1;
    const float* W2t = ws_f + WS_W2T; const float* b2f = ws_f + WS_B2;

    if (t < 64) {
        int ctr = t >> 5;
        sidx[ctr][t & 31] = ball[((size_t)b * NM + m0 + ctr) * NK + (t & 31)];
    }
    __syncthreads();

    const float* Xp = xyz + (size_t)b * NPT * 3;
    if (g < 6) {
        int ctr = g / 3, dim = g % 3;
        float cc = nxyz[((size_t)b * NM + m0 + ctr) * 3 + dim];
        u[ctr][dim][k] = Xp[sidx[ctr][k] * 3 + dim] - cc;
    }
    const float* Fp = feats + (size_t)b * 64 * NPT;
#pragma unroll
    for (int i = 0; i < 8; i++) {
        int c = g + 8 * i;
        u[0][3 + c][k] = Fp[(size_t)c * NPT + sidx[0][k]];
        u[1][3 + c][k] = Fp[(size_t)c * NPT + sidx[1][k]];
    }
    __syncthreads();

    // layer 1: 67 -> 64 (reads u rows 0..66, writes h1)
    {
        float acc0[8], acc1[8];
#pragma unroll
        for (int i = 0; i < 8; i++) { acc0[i] = b0f[g * 8 + i]; acc1[i] = acc0[i]; }
#pragma unroll 4
        for (int c = 0; c < 67; c++) {
            float xv0 = u[0][c][k], xv1 = u[1][c][k];
            const float* wr = W0t + c * 64 + g * 8;
            float4 wa = *(const float4*)(wr), wb = *(const float4*)(wr + 4);
            acc0[0] = fmaf(wa.x, xv0, acc0[0]); acc1[0] = fmaf(wa.x, xv1, acc1[0]);
            acc0[1] = fmaf(wa.y, xv0, acc0[1]); acc1[1] = fmaf(wa.y, xv1, acc1[1]);
            acc0[2] = fmaf(wa.z, xv0, acc0[2]); acc1[2] = fmaf(wa.z, xv1, acc1[2]);
            acc0[3] = fmaf(wa.w, xv0, acc0[3]); acc1[3] = fmaf(wa.w, xv1, acc1[3]);
            acc0[4] = fmaf(wb.x, xv0, acc0[4]); acc1[4] = fmaf(wb.x, xv1, acc1[4]);
            acc0[5] = fmaf(wb.y, xv0, acc0[5]); acc1[5] = fmaf(wb.y, xv1, acc1[5]);
            acc0[6] = fmaf(wb.z, xv0, acc0[6]); acc1[6] = fmaf(wb.z, xv1, acc1[6]);
            acc0[7] = fmaf(wb.w, xv0, acc0[7]); acc1[7] = fmaf(wb.w, xv1, acc1[7]);
        }
#pragma unroll
        for (int i = 0; i < 8; i++) {
            h1[0][g * 8 + i][k] = fmaxf(acc0[i], 0.0f);
            h1[1][g * 8 + i][k] = fmaxf(acc1[i], 0.0f);
        }
    }
    __syncthreads();

    // layer 2: 64 -> 128 (reads h1, writes h2 into u; Xs dead)
    {
        float acc0[16], acc1[16];
#pragma unroll
        for (int i = 0; i < 16; i++) { acc0[i] = b1f[g * 16 + i]; acc1[i] = acc0[i]; }
#pragma unroll 4
        for (int c = 0; c < 64; c++) {
            float xv0 = h1[0][c][k], xv1 = h1[1][c][k];
            const float4* wr = (const float4*)(W1t + c * 128 + g * 16);
#pragma unroll
            for (int q = 0; q < 4; q++) {
                float4 wv = wr[q];
                acc0[q * 4 + 0] = fmaf(wv.x, xv0, acc0[q * 4 + 0]); acc1[q * 4 + 0] = fmaf(wv.x, xv1, acc1[q * 4 + 0]);
                acc0[q * 4 + 1] = fmaf(wv.y, xv0, acc0[q * 4 + 1]); acc1[q * 4 + 1] = fmaf(wv.y, xv1, acc1[q * 4 + 1]);
                acc0[q * 4 + 2] = fmaf(wv.z, xv0, acc0[q * 4 + 2]); acc1[q * 4 + 2] = fmaf(wv.z, xv1, acc1[q * 4 + 2]);
                acc0[q * 4 + 3] = fmaf(wv.w, xv0, acc0[q * 4 + 3]); acc1[q * 4 + 3] = fmaf(wv.w, xv1, acc1[q * 4 + 3]);
            }
        }
        __syncthreads();   // ensure all layer-1 reads of u are done before overwrite
#pragma unroll
        for (int i = 0; i < 16; i++) {
            u[0][g * 16 + i][k] = fmaxf(acc0[i], 0.0f);
            u[1][g * 16 + i][k] = fmaxf(acc1[i], 0.0f);
        }
    }
    __syncthreads();

    // layer 3: 128 -> 256 in two half-passes (reads h2 from u), then max over k
#pragma unroll
    for (int half = 0; half < 2; half++) {
        float acc0[16], acc1[16];
#pragma unroll
        for (int i = 0; i < 16; i++) { acc0[i] = b2f[g * 32 + half * 16 + i]; acc1[i] = acc0[i]; }
#pragma unroll 4
        for (int c = 0; c < 128; c++) {
            float xv0 = u[0][c][k], xv1 = u[1][c][k];
            const float4* wr = (const float4*)(W2t + c * 256 + g * 32 + half * 16);
#pragma unroll
            for (int q = 0; q < 4; q++) {
                float4 wv = wr[q];
                acc0[q * 4 + 0] = fmaf(wv.x, xv0, acc0[q * 4 + 0]); acc1[q * 4 + 0] = fmaf(wv.x, xv1, acc1[q * 4 + 0]);
                acc0[q * 4 + 1] = fmaf(wv.y, xv0, acc0[q * 4 + 1]); acc1[q * 4 + 1] = fmaf(wv.y, xv1, acc1[q * 4 + 1]);
                acc0[q * 4 + 2] = fmaf(wv.z, xv0, acc0[q * 4 + 2]); acc1[q * 4 + 2] = fmaf(wv.z, xv1, acc1[q * 4 + 2]);
                acc0[q * 4 + 3] = fmaf(wv.w, xv0, acc0[q * 4 + 3]); acc1[q * 4 + 3] = fmaf(wv.w, xv1, acc1[q * 4 + 3]);
            }
        }
#pragma unroll
        for (int i = 0; i < 16; i++) {
            float v0 = fmaxf(acc0[i], 0.0f);
            float v1 = fmaxf(acc1[i], 0.0f);
#pragma unroll
            for (int off = 16; off >= 1; off >>= 1) {
                v0 = fmaxf(v0, __shfl_xor(v0, off));
                v1 = fmaxf(v1, __shfl_xor(v1, off));
            }
            if (k == 0) {
                size_t o = (size_t)b * 256 + g * 32 + half * 16 + i;
                out_feat[o * NM + m0]     = v0;
                out_feat[o * NM + m0 + 1] = v1;
            }
        }
    }
}

extern "C" void kernel_launch(void* const* d_in, const int* in_sizes, int n_in,
                              void* d_out, int out_size, void* d_ws, size_t ws_size,
                              hipStream_t stream) {
    const float* xyz   = (const float*)d_in[0];
    const float* feats = (const float*)d_in[1];
    const float* W0 = (const float*)d_in[2];  const float* b0 = (const float*)d_in[3];
    const float* s0 = (const float*)d_in[4];  const float* t0 = (const float*)d_in[5];
    const float* W1 = (const float*)d_in[6];  const float* b1 = (const float*)d_in[7];
    const float* s1 = (const float*)d_in[8];  const float* t1 = (const float*)d_in[9];
    const float* W2 = (const float*)d_in[10]; const float* b2 = (const float*)d_in[11];
    const float* s2 = (const float*)d_in[12]; const float* t2 = (const float*)d_in[13];

    float* ws_f = (float*)d_ws;
    int*   idx_ws  = (int*)(ws_f + WS_IDX);
    float* nxyz_ws = ws_f + WS_NXYZ;
    int*   ball_ws = (int*)(ws_f + WS_BALL);

    float* out_f = (float*)d_out;
    float* out_xyz  = out_f + OUT_XYZ;
    float* out_feat = out_f + OUT_FEAT;
    float* out_idxf = out_f + OUT_IDX;

    prep_weights<<<179, 256, 0, stream>>>(W0, b0, s0, t0, W1, b1, s1, t1, W2, b2, s2, t2, ws_f);
    fps10_kernel<<<NB, 1024, 0, stream>>>(xyz, idx_ws);
    gather_newxyz<<<32, 256, 0, stream>>>(xyz, idx_ws, nxyz_ws, out_xyz, out_idxf);
    ball_query_kernel<<<NB * NM, 256, 0, stream>>>(xyz, nxyz_ws, ball_ws);
    fused_mlp_kernel<<<NB * NM / 2, 256, 0, stream>>>(xyz, feats, ws_f, ball_ws, nxyz_ws, out_feat);
}

// Round 19
// 2451.129 us; speedup vs baseline: 1.1367x; 1.0973x over previous
//
#include <hip/hip_runtime.h>
#include <stdint.h>

#define NB 8
#define NPT 16384
#define NM 1024
#define NK 32

// ws layout (float element offsets)
#define WS_W0T 0                    // 67*64 = 4288   W0t[c][o] = W0[o][c]*s0[o]
#define WS_B0  (WS_W0T + 4288)      // 64             b0*s0+t0
#define WS_W1T (WS_B0 + 64)         // 64*128 = 8192
#define WS_B1  (WS_W1T + 8192)      // 128
#define WS_W2T (WS_B1 + 128)        // 128*256 = 32768
#define WS_B2  (WS_W2T + 32768)     // 256
#define WS_IDX (WS_B2 + 256)        // 8192 ints (FPS indices)
#define WS_NXYZ (WS_IDX + 8192)     // 8*1024*3 = 24576 floats
#define WS_BALL (WS_NXYZ + 24576)   // 8*1024*32 = 262144 ints

// out layout (float element offsets)
#define OUT_XYZ 0
#define OUT_FEAT 24576
#define OUT_IDX (24576 + 2097152)

// ---------------- weight prep: transpose + fold BN scale ----------------
__global__ void prep_weights(const float* __restrict__ W0, const float* __restrict__ b0,
                             const float* __restrict__ s0, const float* __restrict__ t0,
                             const float* __restrict__ W1, const float* __restrict__ b1,
                             const float* __restrict__ s1, const float* __restrict__ t1,
                             const float* __restrict__ W2, const float* __restrict__ b2,
                             const float* __restrict__ s2, const float* __restrict__ t2,
                             float* __restrict__ ws) {
    int id = blockIdx.x * 256 + threadIdx.x;
    if (id < 4288) { int c = id >> 6, o = id & 63;  ws[WS_W0T + id] = W0[o * 67 + c] * s0[o]; return; }
    id -= 4288;
    if (id < 64)   { ws[WS_B0 + id] = fmaf(b0[id], s0[id], t0[id]); return; }
    id -= 64;
    if (id < 8192) { int c = id >> 7, o = id & 127; ws[WS_W1T + id] = W1[o * 64 + c] * s1[o]; return; }
    id -= 8192;
    if (id < 128)  { ws[WS_B1 + id] = fmaf(b1[id], s1[id], t1[id]); return; }
    id -= 128;
    if (id < 32768){ int c = id >> 8, o = id & 255; ws[WS_W2T + id] = W2[o * 128 + c] * s2[o]; return; }
    id -= 32768;
    if (id < 256)  { ws[WS_B2 + id] = fmaf(b2[id], s2[id], t2[id]); return; }
}

#define FOREACH16(M) M(0) M(1) M(2) M(3) M(4) M(5) M(6) M(7) \
                     M(8) M(9) M(10) M(11) M(12) M(13) M(14) M(15)

// DPP u32-max step (dpp_ctrl must be an IMMEDIATE -> template param).
template <int CTRL>
__device__ __forceinline__ uint32_t dpp_max_step(uint32_t v) {
    uint32_t o = (uint32_t)__builtin_amdgcn_update_dpp((int)v, (int)v, CTRL, 0xf, 0xf, false);
    return v > o ? v : o;
}
__device__ __forceinline__ uint32_t wave_max_u32(uint32_t v) {
    v = dpp_max_step<0x111>(v);
    v = dpp_max_step<0x112>(v);
    v = dpp_max_step<0x114>(v);
    v = dpp_max_step<0x118>(v);
    v = dpp_max_step<0x142>(v);
    v = dpp_max_step<0x143>(v);
    return v;
}
__device__ __forceinline__ uint32_t row_max_u32(uint32_t v) {
    v = dpp_max_step<0x111>(v);
    v = dpp_max_step<0x112>(v);
    v = dpp_max_step<0x114>(v);
    v = dpp_max_step<0x118>(v);
    return v;
}

// ---------------- farthest point sampling v10 (R18: 1760us, VALUBusy 97% of the
// 8-CU issue ceiling -- at its structural roofline; unchanged) ----------------
__global__ __attribute__((amdgpu_flat_work_group_size(1024, 1024)))
void fps10_kernel(const float* __restrict__ xyz, int* __restrict__ out_idx) {
    __shared__ float2 pxy[NPT];          // 128 KB
    __shared__ uint2 s_red[2][16];       // {lo=~idx, hi=dist bits} per wave
    int b = blockIdx.x, t = threadIdx.x;
    const float* __restrict__ Xp = xyz + (size_t)b * NPT * 3;

#define DECL_PT(j) float pz##j, dd##j;
    FOREACH16(DECL_PT)
#undef DECL_PT

#define LOAD_PT(j) { int p = t + (j) * 1024; \
        float x = Xp[p * 3 + 0], y = Xp[p * 3 + 1]; \
        pz##j = Xp[p * 3 + 2]; \
        pxy[p] = make_float2(x, y); \
        dd##j = 1e10f; }
    FOREACH16(LOAD_PT)
#undef LOAD_PT
    __syncthreads();

    int farthest = 0;
    float cx = Xp[0], cy = Xp[1], cz = Xp[2];
    int lane = t & 63, w = t >> 6;
    for (int it = 0; it < NM; ++it) {
        if (t == 0) out_idx[b * NM + it] = farthest;
        float best = -1.0f; int bi = 0;
#define STEP_PT(j) { \
        float2 q = pxy[t + (j) * 1024]; \
        float dx = __fsub_rn(q.x, cx); \
        float dy = __fsub_rn(q.y, cy); \
        float dz = __fsub_rn(pz##j, cz); \
        float d  = __fadd_rn(__fadd_rn(__fmul_rn(dx, dx), __fmul_rn(dy, dy)), __fmul_rn(dz, dz)); \
        dd##j = fminf(dd##j, d); \
        if (dd##j > best) { best = dd##j; bi = t + (j) * 1024; } }
        FOREACH16(STEP_PT)
#undef STEP_PT
        uint32_t bbits = __float_as_uint(best);
        uint32_t wmax = __builtin_amdgcn_readlane(wave_max_u32(bbits), 63);
        uint32_t cand = (bbits == wmax) ? ~(uint32_t)bi : 0u;
        uint32_t cwin = __builtin_amdgcn_readlane(wave_max_u32(cand), 63);
        if (lane == 0) s_red[it & 1][w] = make_uint2(cwin, wmax);
        __syncthreads();
        uint2 e = s_red[it & 1][lane & 15];
        uint32_t hmax = __builtin_amdgcn_readlane(row_max_u32(e.y), 15);
        uint32_t c2 = (e.y == hmax) ? e.x : 0u;
        uint32_t c2w = __builtin_amdgcn_readlane(row_max_u32(c2), 15);
        int widx = (int)(~c2w);
        farthest = widx;
        float2 cc = pxy[widx];
        cx = cc.x; cy = cc.y;
        cz = Xp[(size_t)widx * 3 + 2];
    }
}

// ---------------- gather new_xyz + emit indices as float ----------------
__global__ void gather_newxyz(const float* __restrict__ xyz, const int* __restrict__ idx_ws,
                              float* __restrict__ nxyz_ws, float* __restrict__ out_xyz,
                              float* __restrict__ out_idx_f) {
    int id = blockIdx.x * 256 + threadIdx.x;
    if (id >= NB * NM) return;
    int b = id / NM;
    int p = idx_ws[id];
    const float* Xp = xyz + ((size_t)b * NPT + p) * 3;
    float x = Xp[0], y = Xp[1], z = Xp[2];
    nxyz_ws[id * 3 + 0] = x; nxyz_ws[id * 3 + 1] = y; nxyz_ws[id * 3 + 2] = z;
    out_xyz[id * 3 + 0] = x; out_xyz[id * 3 + 1] = y; out_xyz[id * 3 + 2] = z;
    out_idx_f[id] = (float)p;
}

// ---------------- ball query: first 32 in-radius indices (ascending) ----------------
__global__ __launch_bounds__(256) void ball_query_kernel(const float* __restrict__ xyz,
                                                         const float* __restrict__ nxyz,
                                                         int* __restrict__ ball) {
    int blk = blockIdx.x;
    int b = blk >> 10;
    int t = threadIdx.x;
    const float* Xp = xyz + (size_t)b * NPT * 3;
    float cx = nxyz[blk * 3 + 0], cy = nxyz[blk * 3 + 1], cz = nxyz[blk * 3 + 2];
    const float r2 = (float)(0.4 * 0.4);
    uint64_t mask = 0;
    int base = t * 64;
    const float4* q = (const float4*)(Xp + (size_t)base * 3);
#pragma unroll 4
    for (int c = 0; c < 16; c++) {
        float4 A = q[c * 3 + 0], B = q[c * 3 + 1], C = q[c * 3 + 2];
        float xs[4] = {A.x, A.w, B.z, C.y};
        float ys[4] = {A.y, B.x, B.w, C.z};
        float zs[4] = {A.z, B.y, C.x, C.w};
#pragma unroll
        for (int u = 0; u < 4; u++) {
            float dx = __fsub_rn(xs[u], cx);
            float dy = __fsub_rn(ys[u], cy);
            float dz = __fsub_rn(zs[u], cz);
            float d2 = __fadd_rn(__fadd_rn(__fmul_rn(dx, dx), __fmul_rn(dy, dy)), __fmul_rn(dz, dz));
            if (d2 <= r2) mask |= (1ull << (c * 4 + u));
        }
    }
    int cnt = __popcll(mask);
    int scan = cnt;
    for (int off = 1; off < 64; off <<= 1) {
        int nv = __shfl_up(scan, off);
        if ((t & 63) >= off) scan += nv;
    }
    __shared__ int s_wsum[4];
    __shared__ int s_hit[32];
    int w = t >> 6;
    if ((t & 63) == 63) s_wsum[w] = scan;
    __syncthreads();
    int woff = 0;
    for (int i = 0; i < 4; i++) if (i < w) woff += s_wsum[i];
    int excl = woff + scan - cnt;
    uint64_t mm = mask; int pos = excl;
    while (mm && pos < 32) {
        int j = __ffsll((long long)mm) - 1;
        s_hit[pos] = base + j;
        pos++;
        mm &= mm - 1;
    }
    __syncthreads();
    int total = s_wsum[0] + s_wsum[1] + s_wsum[2] + s_wsum[3];
    if (t < 32) {
        int first = s_hit[0];
        ball[blk * NK + t] = (t < total) ? s_hit[t] : first;
    }
}

// ---------------- fused group + 3xMLP + max over K ----------------
// R19 change: weight loads were per-thread VMEM float4 chains (L2 ~200cyc) -- the
// mlp's dominant latency. But weight rows depend only on the wave's output block:
// remap each layer so wave w owns outputs [w*16 + p*64, +16), lane = (ctr = lane>>5,
// k = lane&31), 16 accs/lane. readfirstlane(ob) -> SGPR (HK technique: compiler
// can't prove t>>6 uniform on its own) -> weight/bias loads become scalar s_load,
// off the VMEM critical path; fma becomes v_fmac v, s, v (1 SGPR read = legal).
// Same fma + ds_read volume as before; only the weight path changes.
// Union buffer u = Xs/h2 -> LDS 48KB -> 3 blocks/CU.
__global__ __attribute__((amdgpu_flat_work_group_size(256, 256), amdgpu_waves_per_eu(3, 3)))
void fused_mlp_kernel(const float* __restrict__ xyz,
                      const float* __restrict__ feats,
                      const float* __restrict__ ws_f,
                      const int* __restrict__ ball,
                      const float* __restrict__ nxyz,
                      float* __restrict__ out_feat) {
    int blk = blockIdx.x;
    int b = blk >> 9;
    int m0 = (blk & 511) * 2;
    int t = threadIdx.x;
    int k = t & 31, g = t >> 5;            // staging mapping (unchanged)
    int lane = t & 63, wv = t >> 6;        // layer mapping: wave wv, lane = (ctr,k2)
    int ctr = lane >> 5, k2 = lane & 31;
    __shared__ float u[2][128][32];        // Xs (rows 0..66) then h2 (rows 0..127)
    __shared__ float h1[2][64][32];
    __shared__ int sidx[2][32];
    const float* W0t = ws_f + WS_W0T; const float* b0f = ws_f + WS_B0;
    const float* W1t = ws_f + WS_W1T; const float* b1f = ws_f + WS_B1;
    const float* W2t = ws_f + WS_W2T; const float* b2f = ws_f + WS_B2;

    if (t < 64) {
        int c2 = t >> 5;
        sidx[c2][t & 31] = ball[((size_t)b * NM + m0 + c2) * NK + (t & 31)];
    }
    __syncthreads();

    const float* Xp = xyz + (size_t)b * NPT * 3;
    if (g < 6) {
        int c2 = g / 3, dim = g % 3;
        float cc = nxyz[((size_t)b * NM + m0 + c2) * 3 + dim];
        u[c2][dim][k] = Xp[sidx[c2][k] * 3 + dim] - cc;
    }
    const float* Fp = feats + (size_t)b * 64 * NPT;
#pragma unroll
    for (int i = 0; i < 8; i++) {
        int c = g + 8 * i;
        u[0][3 + c][k] = Fp[(size_t)c * NPT + sidx[0][k]];
        u[1][3 + c][k] = Fp[(size_t)c * NPT + sidx[1][k]];
    }
    __syncthreads();

    // layer 1: 67 -> 64. Wave wv owns outputs [wv*16, +16); lane handles (ctr,k2).
    {
        int ob = __builtin_amdgcn_readfirstlane(wv * 16);   // SGPR output base
        float acc[16];
#pragma unroll
        for (int i = 0; i < 16; i++) acc[i] = b0f[ob + i];
#pragma unroll 4
        for (int c = 0; c < 67; c++) {
            float xv = u[ctr][c][k2];
            const float* wr = W0t + c * 64 + ob;            // wave-uniform -> s_load
#pragma unroll
            for (int i = 0; i < 16; i++) acc[i] = fmaf(wr[i], xv, acc[i]);
        }
#pragma unroll
        for (int i = 0; i < 16; i++) h1[ctr][ob + i][k2] = fmaxf(acc[i], 0.0f);
    }
    __syncthreads();

    // layer 2: 64 -> 128 in 2 passes. Wave wv owns outputs [wv*16 + p*64, +16).
#pragma unroll
    for (int p = 0; p < 2; p++) {
        int ob = __builtin_amdgcn_readfirstlane(wv * 16 + p * 64);
        float acc[16];
#pragma unroll
        for (int i = 0; i < 16; i++) acc[i] = b1f[ob + i];
#pragma unroll 4
        for (int c = 0; c < 64; c++) {
            float xv = h1[ctr][c][k2];
            const float* wr = W1t + c * 128 + ob;           // wave-uniform -> s_load
#pragma unroll
            for (int i = 0; i < 16; i++) acc[i] = fmaf(wr[i], xv, acc[i]);
        }
        // u's Xs content was last read in layer 1 (before the barrier above) -> safe
#pragma unroll
        for (int i = 0; i < 16; i++) u[ctr][ob + i][k2] = fmaxf(acc[i], 0.0f);
    }
    __syncthreads();

    // layer 3: 128 -> 256 in 4 passes + max over k2 (32-lane group reduce).
#pragma unroll
    for (int p = 0; p < 4; p++) {
        int ob = __builtin_amdgcn_readfirstlane(wv * 16 + p * 64);
        float acc[16];
#pragma unroll
        for (int i = 0; i < 16; i++) acc[i] = b2f[ob + i];
#pragma unroll 4
        for (int c = 0; c < 128; c++) {
            float xv = u[ctr][c][k2];
            const float* wr = W2t + c * 256 + ob;           // wave-uniform -> s_load
#pragma unroll
            for (int i = 0; i < 16; i++) acc[i] = fmaf(wr[i], xv, acc[i]);
        }
#pragma unroll
        for (int i = 0; i < 16; i++) {
            float v = fmaxf(acc[i], 0.0f);
#pragma unroll
            for (int off = 16; off >= 1; off >>= 1) v = fmaxf(v, __shfl_xor(v, off));
            if (k2 == 0) {
                size_t o = (size_t)b * 256 + ob + i;
                out_feat[o * NM + m0 + ctr] = v;
            }
        }
    }
}

extern "C" void kernel_launch(void* const* d_in, const int* in_sizes, int n_in,
                              void* d_out, int out_size, void* d_ws, size_t ws_size,
                              hipStream_t stream) {
    const float* xyz   = (const float*)d_in[0];
    const float* feats = (const float*)d_in[1];
    const float* W0 = (const float*)d_in[2];  const float* b0 = (const float*)d_in[3];
    const float* s0 = (const float*)d_in[4];  const float* t0 = (const float*)d_in[5];
    const float* W1 = (const float*)d_in[6];  const float* b1 = (const float*)d_in[7];
    const float* s1 = (const float*)d_in[8];  const float* t1 = (const float*)d_in[9];
    const float* W2 = (const float*)d_in[10]; const float* b2 = (const float*)d_in[11];
    const float* s2 = (const float*)d_in[12]; const float* t2 = (const float*)d_in[13];

    float* ws_f = (float*)d_ws;
    int*   idx_ws  = (int*)(ws_f + WS_IDX);
    float* nxyz_ws = ws_f + WS_NXYZ;
    int*   ball_ws = (int*)(ws_f + WS_BALL);

    float* out_f = (float*)d_out;
    float* out_xyz  = out_f + OUT_XYZ;
    float* out_feat = out_f + OUT_FEAT;
    float* out_idxf = out_f + OUT_IDX;

    prep_weights<<<179, 256, 0, stream>>>(W0, b0, s0, t0, W1, b1, s1, t1, W2, b2, s2, t2, ws_f);
    fps10_kernel<<<NB, 1024, 0, stream>>>(xyz, idx_ws);
    gather_newxyz<<<32, 256, 0, stream>>>(xyz, idx_ws, nxyz_ws, out_xyz, out_idxf);
    ball_query_kernel<<<NB * NM, 256, 0, stream>>>(xyz, nxyz_ws, ball_ws);
    fused_mlp_kernel<<<NB * NM / 2, 256, 0, stream>>>(xyz, feats, ws_f, ball_ws, nxyz_ws, out_feat);
}

// Round 20
// 2326.525 us; speedup vs baseline: 1.1976x; 1.0536x over previous
//
#include <hip/hip_runtime.h>
#include <stdint.h>

#define NB 8
#define NPT 16384
#define NM 1024
#define NK 32

// ws layout (float element offsets)
#define WS_W0T 0                    // 67*64 = 4288   W0t[c][o] = W0[o][c]*s0[o]
#define WS_B0  (WS_W0T + 4288)      // 64             b0*s0+t0
#define WS_W1T (WS_B0 + 64)         // 64*128 = 8192
#define WS_B1  (WS_W1T + 8192)      // 128
#define WS_W2T (WS_B1 + 128)        // 128*256 = 32768
#define WS_B2  (WS_W2T + 32768)     // 256
#define WS_IDX (WS_B2 + 256)        // 8192 ints (FPS indices)
#define WS_NXYZ (WS_IDX + 8192)     // 8*1024*3 = 24576 floats
#define WS_BALL (WS_NXYZ + 24576)   // 8*1024*32 = 262144 ints

// out layout (float element offsets)
#define OUT_XYZ 0
#define OUT_FEAT 24576
#define OUT_IDX (24576 + 2097152)

// ---------------- weight prep: transpose + fold BN scale ----------------
__global__ void prep_weights(const float* __restrict__ W0, const float* __restrict__ b0,
                             const float* __restrict__ s0, const float* __restrict__ t0,
                             const float* __restrict__ W1, const float* __restrict__ b1,
                             const float* __restrict__ s1, const float* __restrict__ t1,
                             const float* __restrict__ W2, const float* __restrict__ b2,
                             const float* __restrict__ s2, const float* __restrict__ t2,
                             float* __restrict__ ws) {
    int id = blockIdx.x * 256 + threadIdx.x;
    if (id < 4288) { int c = id >> 6, o = id & 63;  ws[WS_W0T + id] = W0[o * 67 + c] * s0[o]; return; }
    id -= 4288;
    if (id < 64)   { ws[WS_B0 + id] = fmaf(b0[id], s0[id], t0[id]); return; }
    id -= 64;
    if (id < 8192) { int c = id >> 7, o = id & 127; ws[WS_W1T + id] = W1[o * 64 + c] * s1[o]; return; }
    id -= 8192;
    if (id < 128)  { ws[WS_B1 + id] = fmaf(b1[id], s1[id], t1[id]); return; }
    id -= 128;
    if (id < 32768){ int c = id >> 8, o = id & 255; ws[WS_W2T + id] = W2[o * 128 + c] * s2[o]; return; }
    id -= 32768;
    if (id < 256)  { ws[WS_B2 + id] = fmaf(b2[id], s2[id], t2[id]); return; }
}

#define FOREACH16(M) M(0) M(1) M(2) M(3) M(4) M(5) M(6) M(7) \
                     M(8) M(9) M(10) M(11) M(12) M(13) M(14) M(15)

// DPP u32-max step (dpp_ctrl must be an IMMEDIATE -> template param).
template <int CTRL>
__device__ __forceinline__ uint32_t dpp_max_step(uint32_t v) {
    uint32_t o = (uint32_t)__builtin_amdgcn_update_dpp((int)v, (int)v, CTRL, 0xf, 0xf, false);
    return v > o ? v : o;
}
__device__ __forceinline__ uint32_t wave_max_u32(uint32_t v) {
    v = dpp_max_step<0x111>(v);
    v = dpp_max_step<0x112>(v);
    v = dpp_max_step<0x114>(v);
    v = dpp_max_step<0x118>(v);
    v = dpp_max_step<0x142>(v);
    v = dpp_max_step<0x143>(v);
    return v;
}
__device__ __forceinline__ uint32_t row_max_u32(uint32_t v) {
    v = dpp_max_step<0x111>(v);
    v = dpp_max_step<0x112>(v);
    v = dpp_max_step<0x114>(v);
    v = dpp_max_step<0x118>(v);
    return v;
}

// ---------------- farthest point sampling v10 (R18: 1760us, 97% of the 8-CU
// issue ceiling -- structural roofline; unchanged) ----------------
__global__ __attribute__((amdgpu_flat_work_group_size(1024, 1024)))
void fps10_kernel(const float* __restrict__ xyz, int* __restrict__ out_idx) {
    __shared__ float2 pxy[NPT];          // 128 KB
    __shared__ uint2 s_red[2][16];       // {lo=~idx, hi=dist bits} per wave
    int b = blockIdx.x, t = threadIdx.x;
    const float* __restrict__ Xp = xyz + (size_t)b * NPT * 3;

#define DECL_PT(j) float pz##j, dd##j;
    FOREACH16(DECL_PT)
#undef DECL_PT

#define LOAD_PT(j) { int p = t + (j) * 1024; \
        float x = Xp[p * 3 + 0], y = Xp[p * 3 + 1]; \
        pz##j = Xp[p * 3 + 2]; \
        pxy[p] = make_float2(x, y); \
        dd##j = 1e10f; }
    FOREACH16(LOAD_PT)
#undef LOAD_PT
    __syncthreads();

    int farthest = 0;
    float cx = Xp[0], cy = Xp[1], cz = Xp[2];
    int lane = t & 63, w = t >> 6;
    for (int it = 0; it < NM; ++it) {
        if (t == 0) out_idx[b * NM + it] = farthest;
        float best = -1.0f; int bi = 0;
#define STEP_PT(j) { \
        float2 q = pxy[t + (j) * 1024]; \
        float dx = __fsub_rn(q.x, cx); \
        float dy = __fsub_rn(q.y, cy); \
        float dz = __fsub_rn(pz##j, cz); \
        float d  = __fadd_rn(__fadd_rn(__fmul_rn(dx, dx), __fmul_rn(dy, dy)), __fmul_rn(dz, dz)); \
        dd##j = fminf(dd##j, d); \
        if (dd##j > best) { best = dd##j; bi = t + (j) * 1024; } }
        FOREACH16(STEP_PT)
#undef STEP_PT
        uint32_t bbits = __float_as_uint(best);
        uint32_t wmax = __builtin_amdgcn_readlane(wave_max_u32(bbits), 63);
        uint32_t cand = (bbits == wmax) ? ~(uint32_t)bi : 0u;
        uint32_t cwin = __builtin_amdgcn_readlane(wave_max_u32(cand), 63);
        if (lane == 0) s_red[it & 1][w] = make_uint2(cwin, wmax);
        __syncthreads();
        uint2 e = s_red[it & 1][lane & 15];
        uint32_t hmax = __builtin_amdgcn_readlane(row_max_u32(e.y), 15);
        uint32_t c2 = (e.y == hmax) ? e.x : 0u;
        uint32_t c2w = __builtin_amdgcn_readlane(row_max_u32(c2), 15);
        int widx = (int)(~c2w);
        farthest = widx;
        float2 cc = pxy[widx];
        cx = cc.x; cy = cc.y;
        cz = Xp[(size_t)widx * 3 + 2];
    }
}

// ---------------- gather new_xyz + emit indices as float ----------------
__global__ void gather_newxyz(const float* __restrict__ xyz, const int* __restrict__ idx_ws,
                              float* __restrict__ nxyz_ws, float* __restrict__ out_xyz,
                              float* __restrict__ out_idx_f) {
    int id = blockIdx.x * 256 + threadIdx.x;
    if (id >= NB * NM) return;
    int b = id / NM;
    int p = idx_ws[id];
    const float* Xp = xyz + ((size_t)b * NPT + p) * 3;
    float x = Xp[0], y = Xp[1], z = Xp[2];
    nxyz_ws[id * 3 + 0] = x; nxyz_ws[id * 3 + 1] = y; nxyz_ws[id * 3 + 2] = z;
    out_xyz[id * 3 + 0] = x; out_xyz[id * 3 + 1] = y; out_xyz[id * 3 + 2] = z;
    out_idx_f[id] = (float)p;
}

// ---------------- ball query v2: FOUR centers per block ----------------
// R20 change: each block previously streamed all 196KB of its batch's points from
// L2 for ONE center (8192 blocks -> 1.6GB L2 read traffic, thread = 48 dependent
// 16B loads for ~10 VALU inst each -> latency-bound). Now each block handles 4
// centers: each 4-point chunk is loaded ONCE and tested against all 4 centers.
// Loads /4, per-center math/scan/emit byte-identical (looped, barrier-separated).
__global__ __launch_bounds__(256) void ball_query_kernel(const float* __restrict__ xyz,
                                                         const float* __restrict__ nxyz,
                                                         int* __restrict__ ball) {
    int blk = blockIdx.x;                  // 0..2047
    int b = blk >> 8;                      // 256 blocks per batch
    int m0 = (blk & 255) * 4;              // centers m0..m0+3
    int t = threadIdx.x;
    const float* Xp = xyz + (size_t)b * NPT * 3;
    float cx[4], cy[4], cz[4];
#pragma unroll
    for (int q2 = 0; q2 < 4; q2++) {
        size_t nb2 = ((size_t)b * NM + m0 + q2) * 3;
        cx[q2] = nxyz[nb2 + 0]; cy[q2] = nxyz[nb2 + 1]; cz[q2] = nxyz[nb2 + 2];
    }
    const float r2 = (float)(0.4 * 0.4);
    uint64_t mask[4] = {0, 0, 0, 0};
    int base = t * 64;
    const float4* q = (const float4*)(Xp + (size_t)base * 3);
#pragma unroll 4
    for (int c = 0; c < 16; c++) {
        float4 A = q[c * 3 + 0], B = q[c * 3 + 1], C = q[c * 3 + 2];
        float xs[4] = {A.x, A.w, B.z, C.y};
        float ys[4] = {A.y, B.x, B.w, C.z};
        float zs[4] = {A.z, B.y, C.x, C.w};
#pragma unroll
        for (int u = 0; u < 4; u++) {
#pragma unroll
            for (int ctr = 0; ctr < 4; ctr++) {
                float dx = __fsub_rn(xs[u], cx[ctr]);
                float dy = __fsub_rn(ys[u], cy[ctr]);
                float dz = __fsub_rn(zs[u], cz[ctr]);
                float d2 = __fadd_rn(__fadd_rn(__fmul_rn(dx, dx), __fmul_rn(dy, dy)), __fmul_rn(dz, dz));
                if (d2 <= r2) mask[ctr] |= (1ull << (c * 4 + u));
            }
        }
    }
    __shared__ int s_wsum[4];
    __shared__ int s_hit[32];
    int w = t >> 6;
#pragma unroll
    for (int ctr = 0; ctr < 4; ctr++) {
        uint64_t mk = mask[ctr];
        int cnt = __popcll(mk);
        int scan = cnt;                    // wave inclusive scan
        for (int off = 1; off < 64; off <<= 1) {
            int nv = __shfl_up(scan, off);
            if ((t & 63) >= off) scan += nv;
        }
        if ((t & 63) == 63) s_wsum[w] = scan;
        __syncthreads();
        int woff = 0;
        for (int i = 0; i < 4; i++) if (i < w) woff += s_wsum[i];
        int excl = woff + scan - cnt;      // exclusive prefix in point-index order
        uint64_t mm = mk; int pos = excl;
        while (mm && pos < 32) {
            int j = __ffsll((long long)mm) - 1;
            s_hit[pos] = base + j;
            pos++;
            mm &= mm - 1;
        }
        __syncthreads();
        int total = s_wsum[0] + s_wsum[1] + s_wsum[2] + s_wsum[3];
        if (t < 32) {
            int first = s_hit[0];          // total >= 1 (center itself at d2=0)
            ball[((size_t)b * NM + m0 + ctr) * NK + t] = (t < total) ? s_hit[t] : first;
        }
        __syncthreads();                   // s_hit/s_wsum reused next ctr
    }
}

// ---------------- fused group + 3xMLP + max over K (R19 scalar-weight version) ----------------
__global__ __attribute__((amdgpu_flat_work_group_size(256, 256), amdgpu_waves_per_eu(3, 3)))
void fused_mlp_kernel(const float* __restrict__ xyz,
                      const float* __restrict__ feats,
                      const float* __restrict__ ws_f,
                      const int* __restrict__ ball,
                      const float* __restrict__ nxyz,
                      float* __restrict__ out_feat) {
    int blk = blockIdx.x;
    int b = blk >> 9;
    int m0 = (blk & 511) * 2;
    int t = threadIdx.x;
    int k = t & 31, g = t >> 5;            // staging mapping
    int lane = t & 63, wv = t >> 6;        // layer mapping: wave wv, lane = (ctr,k2)
    int ctr = lane >> 5, k2 = lane & 31;
    __shared__ float u[2][128][32];        // Xs (rows 0..66) then h2 (rows 0..127)
    __shared__ float h1[2][64][32];
    __shared__ int sidx[2][32];
    const float* W0t = ws_f + WS_W0T; const float* b0f = ws_f + WS_B0;
    const float* W1t = ws_f + WS_W1T; const float* b1f = ws_f + WS_B1;
    const float* W2t = ws_f + WS_W2T; const float* b2f = ws_f + WS_B2;

    if (t < 64) {
        int c2 = t >> 5;
        sidx[c2][t & 31] = ball[((size_t)b * NM + m0 + c2) * NK + (t & 31)];
    }
    __syncthreads();

    const float* Xp = xyz + (size_t)b * NPT * 3;
    if (g < 6) {
        int c2 = g / 3, dim = g % 3;
        float cc = nxyz[((size_t)b * NM + m0 + c2) * 3 + dim];
        u[c2][dim][k] = Xp[sidx[c2][k] * 3 + dim] - cc;
    }
    const float* Fp = feats + (size_t)b * 64 * NPT;
#pragma unroll
    for (int i = 0; i < 8; i++) {
        int c = g + 8 * i;
        u[0][3 + c][k] = Fp[(size_t)c * NPT + sidx[0][k]];
        u[1][3 + c][k] = Fp[(size_t)c * NPT + sidx[1][k]];
    }
    __syncthreads();

    // layer 1: 67 -> 64. Wave wv owns outputs [wv*16, +16); lane handles (ctr,k2).
    {
        int ob = __builtin_amdgcn_readfirstlane(wv * 16);   // SGPR output base
        float acc[16];
#pragma unroll
        for (int i = 0; i < 16; i++) acc[i] = b0f[ob + i];
#pragma unroll 4
        for (int c = 0; c < 67; c++) {
            float xv = u[ctr][c][k2];
            const float* wr = W0t + c * 64 + ob;            // wave-uniform -> s_load
#pragma unroll
            for (int i = 0; i < 16; i++) acc[i] = fmaf(wr[i], xv, acc[i]);
        }
#pragma unroll
        for (int i = 0; i < 16; i++) h1[ctr][ob + i][k2] = fmaxf(acc[i], 0.0f);
    }
    __syncthreads();

    // layer 2: 64 -> 128 in 2 passes. Wave wv owns outputs [wv*16 + p*64, +16).
#pragma unroll
    for (int p = 0; p < 2; p++) {
        int ob = __builtin_amdgcn_readfirstlane(wv * 16 + p * 64);
        float acc[16];
#pragma unroll
        for (int i = 0; i < 16; i++) acc[i] = b1f[ob + i];
#pragma unroll 4
        for (int c = 0; c < 64; c++) {
            float xv = h1[ctr][c][k2];
            const float* wr = W1t + c * 128 + ob;           // wave-uniform -> s_load
#pragma unroll
            for (int i = 0; i < 16; i++) acc[i] = fmaf(wr[i], xv, acc[i]);
        }
#pragma unroll
        for (int i = 0; i < 16; i++) u[ctr][ob + i][k2] = fmaxf(acc[i], 0.0f);
    }
    __syncthreads();

    // layer 3: 128 -> 256 in 4 passes + max over k2 (32-lane group reduce).
#pragma unroll
    for (int p = 0; p < 4; p++) {
        int ob = __builtin_amdgcn_readfirstlane(wv * 16 + p * 64);
        float acc[16];
#pragma unroll
        for (int i = 0; i < 16; i++) acc[i] = b2f[ob + i];
#pragma unroll 4
        for (int c = 0; c < 128; c++) {
            float xv = u[ctr][c][k2];
            const float* wr = W2t + c * 256 + ob;           // wave-uniform -> s_load
#pragma unroll
            for (int i = 0; i < 16; i++) acc[i] = fmaf(wr[i], xv, acc[i]);
        }
#pragma unroll
        for (int i = 0; i < 16; i++) {
            float v = fmaxf(acc[i], 0.0f);
#pragma unroll
            for (int off = 16; off >= 1; off >>= 1) v = fmaxf(v, __shfl_xor(v, off));
            if (k2 == 0) {
                size_t o = (size_t)b * 256 + ob + i;
                out_feat[o * NM + m0 + ctr] = v;
            }
        }
    }
}

extern "C" void kernel_launch(void* const* d_in, const int* in_sizes, int n_in,
                              void* d_out, int out_size, void* d_ws, size_t ws_size,
                              hipStream_t stream) {
    const float* xyz   = (const float*)d_in[0];
    const float* feats = (const float*)d_in[1];
    const float* W0 = (const float*)d_in[2];  const float* b0 = (const float*)d_in[3];
    const float* s0 = (const float*)d_in[4];  const float* t0 = (const float*)d_in[5];
    const float* W1 = (const float*)d_in[6];  const float* b1 = (const float*)d_in[7];
    const float* s1 = (const float*)d_in[8];  const float* t1 = (const float*)d_in[9];
    const float* W2 = (const float*)d_in[10]; const float* b2 = (const float*)d_in[11];
    const float* s2 = (const float*)d_in[12]; const float* t2 = (const float*)d_in[13];

    float* ws_f = (float*)d_ws;
    int*   idx_ws  = (int*)(ws_f + WS_IDX);
    float* nxyz_ws = ws_f + WS_NXYZ;
    int*   ball_ws = (int*)(ws_f + WS_BALL);

    float* out_f = (float*)d_out;
    float* out_xyz  = out_f + OUT_XYZ;
    float* out_feat = out_f + OUT_FEAT;
    float* out_idxf = out_f + OUT_IDX;

    prep_weights<<<179, 256, 0, stream>>>(W0, b0, s0, t0, W1, b1, s1, t1, W2, b2, s2, t2, ws_f);
    fps10_kernel<<<NB, 1024, 0, stream>>>(xyz, idx_ws);
    gather_newxyz<<<32, 256, 0, stream>>>(xyz, idx_ws, nxyz_ws, out_xyz, out_idxf);
    ball_query_kernel<<<NB * NM / 4, 256, 0, stream>>>(xyz, nxyz_ws, ball_ws);
    fused_mlp_kernel<<<NB * NM / 2, 256, 0, stream>>>(xyz, feats, ws_f, ball_ws, nxyz_ws, out_feat);
}

// Round 21
// 2207.532 us; speedup vs baseline: 1.2622x; 1.0539x over previous
//
#include <hip/hip_runtime.h>
#include <stdint.h>

#define NB 8
#define NPT 16384
#define NM 1024
#define NK 32

// ws layout (float element offsets)
#define WS_W0T 0                    // 67*64 = 4288   W0t[c][o] = W0[o][c]*s0[o]
#define WS_B0  (WS_W0T + 4288)      // 64             b0*s0+t0
#define WS_W1T (WS_B0 + 64)         // 64*128 = 8192
#define WS_B1  (WS_W1T + 8192)      // 128
#define WS_W2T (WS_B1 + 128)        // 128*256 = 32768
#define WS_B2  (WS_W2T + 32768)     // 256
#define WS_IDX (WS_B2 + 256)        // 8192 ints (FPS indices)
#define WS_NXYZ (WS_IDX + 8192)     // 8*1024*3 = 24576 floats
#define WS_BALL (WS_NXYZ + 24576)   // 8*1024*32 = 262144 ints

// out layout (float element offsets)
#define OUT_XYZ 0
#define OUT_FEAT 24576
#define OUT_IDX (24576 + 2097152)

// ---------------- weight prep: transpose + fold BN scale ----------------
__global__ void prep_weights(const float* __restrict__ W0, const float* __restrict__ b0,
                             const float* __restrict__ s0, const float* __restrict__ t0,
                             const float* __restrict__ W1, const float* __restrict__ b1,
                             const float* __restrict__ s1, const float* __restrict__ t1,
                             const float* __restrict__ W2, const float* __restrict__ b2,
                             const float* __restrict__ s2, const float* __restrict__ t2,
                             float* __restrict__ ws) {
    int id = blockIdx.x * 256 + threadIdx.x;
    if (id < 4288) { int c = id >> 6, o = id & 63;  ws[WS_W0T + id] = W0[o * 67 + c] * s0[o]; return; }
    id -= 4288;
    if (id < 64)   { ws[WS_B0 + id] = fmaf(b0[id], s0[id], t0[id]); return; }
    id -= 64;
    if (id < 8192) { int c = id >> 7, o = id & 127; ws[WS_W1T + id] = W1[o * 64 + c] * s1[o]; return; }
    id -= 8192;
    if (id < 128)  { ws[WS_B1 + id] = fmaf(b1[id], s1[id], t1[id]); return; }
    id -= 128;
    if (id < 32768){ int c = id >> 8, o = id & 255; ws[WS_W2T + id] = W2[o * 128 + c] * s2[o]; return; }
    id -= 32768;
    if (id < 256)  { ws[WS_B2 + id] = fmaf(b2[id], s2[id], t2[id]); return; }
}

#define FOREACH16(M) M(0) M(1) M(2) M(3) M(4) M(5) M(6) M(7) \
                     M(8) M(9) M(10) M(11) M(12) M(13) M(14) M(15)

// DPP u32-max step (dpp_ctrl must be an IMMEDIATE -> template param).
template <int CTRL>
__device__ __forceinline__ uint32_t dpp_max_step(uint32_t v) {
    uint32_t o = (uint32_t)__builtin_amdgcn_update_dpp((int)v, (int)v, CTRL, 0xf, 0xf, false);
    return v > o ? v : o;
}
__device__ __forceinline__ uint32_t wave_max_u32(uint32_t v) {
    v = dpp_max_step<0x111>(v);
    v = dpp_max_step<0x112>(v);
    v = dpp_max_step<0x114>(v);
    v = dpp_max_step<0x118>(v);
    v = dpp_max_step<0x142>(v);
    v = dpp_max_step<0x143>(v);
    return v;
}
__device__ __forceinline__ uint32_t row_max_u32(uint32_t v) {
    v = dpp_max_step<0x111>(v);
    v = dpp_max_step<0x112>(v);
    v = dpp_max_step<0x114>(v);
    v = dpp_max_step<0x118>(v);
    return v;
}

// ---------------- farthest point sampling v10 (R18: 1760us, 97% of the 8-CU
// issue ceiling -- structural roofline; unchanged) ----------------
__global__ __attribute__((amdgpu_flat_work_group_size(1024, 1024)))
void fps10_kernel(const float* __restrict__ xyz, int* __restrict__ out_idx) {
    __shared__ float2 pxy[NPT];          // 128 KB
    __shared__ uint2 s_red[2][16];       // {lo=~idx, hi=dist bits} per wave
    int b = blockIdx.x, t = threadIdx.x;
    const float* __restrict__ Xp = xyz + (size_t)b * NPT * 3;

#define DECL_PT(j) float pz##j, dd##j;
    FOREACH16(DECL_PT)
#undef DECL_PT

#define LOAD_PT(j) { int p = t + (j) * 1024; \
        float x = Xp[p * 3 + 0], y = Xp[p * 3 + 1]; \
        pz##j = Xp[p * 3 + 2]; \
        pxy[p] = make_float2(x, y); \
        dd##j = 1e10f; }
    FOREACH16(LOAD_PT)
#undef LOAD_PT
    __syncthreads();

    int farthest = 0;
    float cx = Xp[0], cy = Xp[1], cz = Xp[2];
    int lane = t & 63, w = t >> 6;
    for (int it = 0; it < NM; ++it) {
        if (t == 0) out_idx[b * NM + it] = farthest;
        float best = -1.0f; int bi = 0;
#define STEP_PT(j) { \
        float2 q = pxy[t + (j) * 1024]; \
        float dx = __fsub_rn(q.x, cx); \
        float dy = __fsub_rn(q.y, cy); \
        float dz = __fsub_rn(pz##j, cz); \
        float d  = __fadd_rn(__fadd_rn(__fmul_rn(dx, dx), __fmul_rn(dy, dy)), __fmul_rn(dz, dz)); \
        dd##j = fminf(dd##j, d); \
        if (dd##j > best) { best = dd##j; bi = t + (j) * 1024; } }
        FOREACH16(STEP_PT)
#undef STEP_PT
        uint32_t bbits = __float_as_uint(best);
        uint32_t wmax = __builtin_amdgcn_readlane(wave_max_u32(bbits), 63);
        uint32_t cand = (bbits == wmax) ? ~(uint32_t)bi : 0u;
        uint32_t cwin = __builtin_amdgcn_readlane(wave_max_u32(cand), 63);
        if (lane == 0) s_red[it & 1][w] = make_uint2(cwin, wmax);
        __syncthreads();
        uint2 e = s_red[it & 1][lane & 15];
        uint32_t hmax = __builtin_amdgcn_readlane(row_max_u32(e.y), 15);
        uint32_t c2 = (e.y == hmax) ? e.x : 0u;
        uint32_t c2w = __builtin_amdgcn_readlane(row_max_u32(c2), 15);
        int widx = (int)(~c2w);
        farthest = widx;
        float2 cc = pxy[widx];
        cx = cc.x; cy = cc.y;
        cz = Xp[(size_t)widx * 3 + 2];
    }
}

// ---------------- gather new_xyz + emit indices as float ----------------
__global__ void gather_newxyz(const float* __restrict__ xyz, const int* __restrict__ idx_ws,
                              float* __restrict__ nxyz_ws, float* __restrict__ out_xyz,
                              float* __restrict__ out_idx_f) {
    int id = blockIdx.x * 256 + threadIdx.x;
    if (id >= NB * NM) return;
    int b = id / NM;
    int p = idx_ws[id];
    const float* Xp = xyz + ((size_t)b * NPT + p) * 3;
    float x = Xp[0], y = Xp[1], z = Xp[2];
    nxyz_ws[id * 3 + 0] = x; nxyz_ws[id * 3 + 1] = y; nxyz_ws[id * 3 + 2] = z;
    out_xyz[id * 3 + 0] = x; out_xyz[id * 3 + 1] = y; out_xyz[id * 3 + 2] = z;
    out_idx_f[id] = (float)p;
}

// ---------------- ball query v3: EIGHT centers per block ----------------
// R20 (4-ctr) proved load-sharing is the lever (+125us). R21: 8 centers/block ->
// point loads /2 again (1024 blocks x 196KB = 201MB L2 reads); per-center VALU
// doubles but stays small (~34us chip-total). Per-center math/scan/emit remains
// byte-identical (looped, barrier-separated; masks in 8 statically-indexed u64s).
__global__ __launch_bounds__(256) void ball_query_kernel(const float* __restrict__ xyz,
                                                         const float* __restrict__ nxyz,
                                                         int* __restrict__ ball) {
    int blk = blockIdx.x;                  // 0..1023
    int b = blk >> 7;                      // 128 blocks per batch
    int m0 = (blk & 127) * 8;              // centers m0..m0+7
    int t = threadIdx.x;
    const float* Xp = xyz + (size_t)b * NPT * 3;
    float cx[8], cy[8], cz[8];
#pragma unroll
    for (int q2 = 0; q2 < 8; q2++) {
        size_t nb2 = ((size_t)b * NM + m0 + q2) * 3;
        cx[q2] = nxyz[nb2 + 0]; cy[q2] = nxyz[nb2 + 1]; cz[q2] = nxyz[nb2 + 2];
    }
    const float r2 = (float)(0.4 * 0.4);
    uint64_t mask[8] = {0, 0, 0, 0, 0, 0, 0, 0};
    int base = t * 64;
    const float4* q = (const float4*)(Xp + (size_t)base * 3);
#pragma unroll 4
    for (int c = 0; c < 16; c++) {
        float4 A = q[c * 3 + 0], B = q[c * 3 + 1], C = q[c * 3 + 2];
        float xs[4] = {A.x, A.w, B.z, C.y};
        float ys[4] = {A.y, B.x, B.w, C.z};
        float zs[4] = {A.z, B.y, C.x, C.w};
#pragma unroll
        for (int u = 0; u < 4; u++) {
#pragma unroll
            for (int ctr = 0; ctr < 8; ctr++) {
                float dx = __fsub_rn(xs[u], cx[ctr]);
                float dy = __fsub_rn(ys[u], cy[ctr]);
                float dz = __fsub_rn(zs[u], cz[ctr]);
                float d2 = __fadd_rn(__fadd_rn(__fmul_rn(dx, dx), __fmul_rn(dy, dy)), __fmul_rn(dz, dz));
                if (d2 <= r2) mask[ctr] |= (1ull << (c * 4 + u));
            }
        }
    }
    __shared__ int s_wsum[4];
    __shared__ int s_hit[32];
    int w = t >> 6;
#pragma unroll
    for (int ctr = 0; ctr < 8; ctr++) {
        uint64_t mk = mask[ctr];
        int cnt = __popcll(mk);
        int scan = cnt;                    // wave inclusive scan
        for (int off = 1; off < 64; off <<= 1) {
            int nv = __shfl_up(scan, off);
            if ((t & 63) >= off) scan += nv;
        }
        if ((t & 63) == 63) s_wsum[w] = scan;
        __syncthreads();
        int woff = 0;
        for (int i = 0; i < 4; i++) if (i < w) woff += s_wsum[i];
        int excl = woff + scan - cnt;      // exclusive prefix in point-index order
        uint64_t mm = mk; int pos = excl;
        while (mm && pos < 32) {
            int j = __ffsll((long long)mm) - 1;
            s_hit[pos] = base + j;
            pos++;
            mm &= mm - 1;
        }
        __syncthreads();
        int total = s_wsum[0] + s_wsum[1] + s_wsum[2] + s_wsum[3];
        if (t < 32) {
            int first = s_hit[0];          // total >= 1 (center itself at d2=0)
            ball[((size_t)b * NM + m0 + ctr) * NK + t] = (t < total) ? s_hit[t] : first;
        }
        __syncthreads();                   // s_hit/s_wsum reused next ctr
    }
}

// ---------------- fused group + 3xMLP + max over K ----------------
// R21 change: h1 folded into the union buffer at rows 67..130 -> LDS 48KB -> 34KB
// -> 4 blocks/CU (16 waves, +33% latency hiding on the h-matrix ds_read chains).
// Race audit: L1 reads Xs rows 0..66, writes rows 67..130 (disjoint). L2 pass p
// reads rows 67..130 into regs -> barrier -> writes rows [wv*16+p*64,+16)
// (p=0: rows 0..63, disjoint from h1; p=1: rows 64..127, h1 dead after the
// barrier guarantees all reads done). L3 reads rows 0..127 after final barrier.
// Weights stay on the scalar path (readfirstlane output base, R19: -238us).
__global__ __attribute__((amdgpu_flat_work_group_size(256, 256), amdgpu_waves_per_eu(4, 4)))
void fused_mlp_kernel(const float* __restrict__ xyz,
                      const float* __restrict__ feats,
                      const float* __restrict__ ws_f,
                      const int* __restrict__ ball,
                      const float* __restrict__ nxyz,
                      float* __restrict__ out_feat) {
    int blk = blockIdx.x;
    int b = blk >> 9;
    int m0 = (blk & 511) * 2;
    int t = threadIdx.x;
    int k = t & 31, g = t >> 5;            // staging mapping
    int lane = t & 63, wv = t >> 6;        // layer mapping: wave wv, lane = (ctr,k2)
    int ctr = lane >> 5, k2 = lane & 31;
    __shared__ float u[2][131][32];        // rows 0..66: Xs -> h2 rows 0..127; rows 67..130: h1
    __shared__ int sidx[2][32];
    const float* W0t = ws_f + WS_W0T; const float* b0f = ws_f + WS_B0;
    const float* W1t = ws_f + WS_W1T; const float* b1f = ws_f + WS_B1;
    const float* W2t = ws_f + WS_W2T; const float* b2f = ws_f + WS_B2;

    if (t < 64) {
        int c2 = t >> 5;
        sidx[c2][t & 31] = ball[((size_t)b * NM + m0 + c2) * NK + (t & 31)];
    }
    __syncthreads();

    const float* Xp = xyz + (size_t)b * NPT * 3;
    if (g < 6) {
        int c2 = g / 3, dim = g % 3;
        float cc = nxyz[((size_t)b * NM + m0 + c2) * 3 + dim];
        u[c2][dim][k] = Xp[sidx[c2][k] * 3 + dim] - cc;
    }
    const float* Fp = feats + (size_t)b * 64 * NPT;
#pragma unroll
    for (int i = 0; i < 8; i++) {
        int c = g + 8 * i;
        u[0][3 + c][k] = Fp[(size_t)c * NPT + sidx[0][k]];
        u[1][3 + c][k] = Fp[(size_t)c * NPT + sidx[1][k]];
    }
    __syncthreads();

    // layer 1: 67 -> 64. Wave wv owns outputs [wv*16, +16); h1 goes to u rows 67+o.
    {
        int ob = __builtin_amdgcn_readfirstlane(wv * 16);   // SGPR output base
        float acc[16];
#pragma unroll
        for (int i = 0; i < 16; i++) acc[i] = b0f[ob + i];
#pragma unroll 4
        for (int c = 0; c < 67; c++) {
            float xv = u[ctr][c][k2];
            const float* wr = W0t + c * 64 + ob;            // wave-uniform -> s_load
#pragma unroll
            for (int i = 0; i < 16; i++) acc[i] = fmaf(wr[i], xv, acc[i]);
        }
#pragma unroll
        for (int i = 0; i < 16; i++) u[ctr][67 + ob + i][k2] = fmaxf(acc[i], 0.0f);
    }
    __syncthreads();

    // layer 2: 64 -> 128 in 2 passes. Reads h1 (rows 67..130), writes h2 (rows 0..127).
#pragma unroll
    for (int p = 0; p < 2; p++) {
        int ob = __builtin_amdgcn_readfirstlane(wv * 16 + p * 64);
        float acc[16];
#pragma unroll
        for (int i = 0; i < 16; i++) acc[i] = b1f[ob + i];
#pragma unroll 4
        for (int c = 0; c < 64; c++) {
            float xv = u[ctr][67 + c][k2];
            const float* wr = W1t + c * 128 + ob;           // wave-uniform -> s_load
#pragma unroll
            for (int i = 0; i < 16; i++) acc[i] = fmaf(wr[i], xv, acc[i]);
        }
        __syncthreads();   // all reads of h1/Xs rows done before this pass overwrites
#pragma unroll
        for (int i = 0; i < 16; i++) u[ctr][ob + i][k2] = fmaxf(acc[i], 0.0f);
    }
    __syncthreads();

    // layer 3: 128 -> 256 in 4 passes + max over k2 (32-lane group reduce).
#pragma unroll
    for (int p = 0; p < 4; p++) {
        int ob = __builtin_amdgcn_readfirstlane(wv * 16 + p * 64);
        float acc[16];
#pragma unroll
        for (int i = 0; i < 16; i++) acc[i] = b2f[ob + i];
#pragma unroll 4
        for (int c = 0; c < 128; c++) {
            float xv = u[ctr][c][k2];
            const float* wr = W2t + c * 256 + ob;           // wave-uniform -> s_load
#pragma unroll
            for (int i = 0; i < 16; i++) acc[i] = fmaf(wr[i], xv, acc[i]);
        }
#pragma unroll
        for (int i = 0; i < 16; i++) {
            float v = fmaxf(acc[i], 0.0f);
#pragma unroll
            for (int off = 16; off >= 1; off >>= 1) v = fmaxf(v, __shfl_xor(v, off));
            if (k2 == 0) {
                size_t o = (size_t)b * 256 + ob + i;
                out_feat[o * NM + m0 + ctr] = v;
            }
        }
    }
}

extern "C" void kernel_launch(void* const* d_in, const int* in_sizes, int n_in,
                              void* d_out, int out_size, void* d_ws, size_t ws_size,
                              hipStream_t stream) {
    const float* xyz   = (const float*)d_in[0];
    const float* feats = (const float*)d_in[1];
    const float* W0 = (const float*)d_in[2];  const float* b0 = (const float*)d_in[3];
    const float* s0 = (const float*)d_in[4];  const float* t0 = (const float*)d_in[5];
    const float* W1 = (const float*)d_in[6];  const float* b1 = (const float*)d_in[7];
    const float* s1 = (const float*)d_in[8];  const float* t1 = (const float*)d_in[9];
    const float* W2 = (const float*)d_in[10]; const float* b2 = (const float*)d_in[11];
    const float* s2 = (const float*)d_in[12]; const float* t2 = (const float*)d_in[13];

    float* ws_f = (float*)d_ws;
    int*   idx_ws  = (int*)(ws_f + WS_IDX);
    float* nxyz_ws = ws_f + WS_NXYZ;
    int*   ball_ws = (int*)(ws_f + WS_BALL);

    float* out_f = (float*)d_out;
    float* out_xyz  = out_f + OUT_XYZ;
    float* out_feat = out_f + OUT_FEAT;
    float* out_idxf = out_f + OUT_IDX;

    prep_weights<<<179, 256, 0, stream>>>(W0, b0, s0, t0, W1, b1, s1, t1, W2, b2, s2, t2, ws_f);
    fps10_kernel<<<NB, 1024, 0, stream>>>(xyz, idx_ws);
    gather_newxyz<<<32, 256, 0, stream>>>(xyz, idx_ws, nxyz_ws, out_xyz, out_idxf);
    ball_query_kernel<<<NB * NM / 8, 256, 0, stream>>>(xyz, nxyz_ws, ball_ws);
    fused_mlp_kernel<<<NB * NM / 2, 256, 0, stream>>>(xyz, feats, ws_f, ball_ws, nxyz_ws, out_feat);
}